// Round 3
// baseline (931.297 us; speedup 1.0000x reference)
//
#include <hip/hip_runtime.h>

#define NNODES 50000
#define RREL 51
#define FIN 32
#define EDIM 32
#define CDIM 16
#define BB 30
#define NNZ_ 2000000

typedef unsigned int uint32;
typedef uint32 u32x2 __attribute__((ext_vector_type(2)));
typedef uint32 u32x4 __attribute__((ext_vector_type(4)));

// ---------- bf16 pack/unpack (manual RNE) ----------
static __device__ __forceinline__ uint32 pack_bf16x2(float a, float b) {
    uint32 ua = __builtin_bit_cast(uint32, a);
    uint32 ub = __builtin_bit_cast(uint32, b);
    ua += 0x7fffu + ((ua >> 16) & 1u);
    ub += 0x7fffu + ((ub >> 16) & 1u);
    return (ua >> 16) | (ub & 0xffff0000u);
}
static __device__ __forceinline__ float unpack_lo(uint32 u) { return __builtin_bit_cast(float, u << 16); }
static __device__ __forceinline__ float unpack_hi(uint32 u) { return __builtin_bit_cast(float, u & 0xffff0000u); }

// ---------------- weight build: w[r] = sum_b comps[r,b] * bases[b] ----------------
__global__ void k_weights(const float* __restrict__ comps1, const float* __restrict__ bases1,
                          const float* __restrict__ comps2, const float* __restrict__ bases2,
                          float* __restrict__ w1, float* __restrict__ w2) {
    int i = blockIdx.x * 256 + threadIdx.x;
    if (i < RREL * FIN * EDIM) {          // (R, F, E)
        int r = i >> 10, fe = i & 1023;
        float acc = 0.f;
#pragma unroll
        for (int b = 0; b < BB; b++) acc += comps1[r * BB + b] * bases1[b * 1024 + fe];
        w1[i] = acc;
    }
    if (i < RREL * EDIM * CDIM) {         // (R, E, C)
        int r = i >> 9, ec = i & 511;
        float acc = 0.f;
#pragma unroll
        for (int b = 0; b < BB; b++) acc += comps2[r * BB + b] * bases2[b * 512 + ec];
        w2[i] = acc;
    }
}

// ---------------- fp32 features -> packed bf16 rows (64 B/row, L2-resident) ----------
__global__ void k_tobf16(const float2* __restrict__ src, uint32* __restrict__ dst, int n2) {
    int i = blockIdx.x * 256 + threadIdx.x;
    if (i < n2) {
        float2 f = src[i];
        dst[i] = pack_bf16x2(f.x, f.y);
    }
}

// ---------------- histograms: per-relation (LDS) + per-dst (global) ----------------
__global__ void k_hist(const int* __restrict__ rows, int* __restrict__ rel_cnt,
                       int* __restrict__ dst_cnt) {
    __shared__ int lc[RREL];
    if (threadIdx.x < RREL) lc[threadIdx.x] = 0;
    __syncthreads();
    int stride = gridDim.x * blockDim.x;
    for (int k = blockIdx.x * blockDim.x + threadIdx.x; k < NNZ_; k += stride) {
        int rw = rows[k];
        int rel = rw / NNODES;
        atomicAdd(&lc[rel], 1);
        atomicAdd(&dst_cnt[rw - rel * NNODES], 1);
    }
    __syncthreads();
    if (threadIdx.x < RREL) atomicAdd(&rel_cnt[threadIdx.x], lc[threadIdx.x]);
}

__global__ void k_prefix(const int* __restrict__ rel_cnt, int* __restrict__ rel_base) {
    if (threadIdx.x == 0) {
        int acc = 0;
        for (int r = 0; r < RREL; r++) { rel_base[r] = acc; acc += rel_cnt[r]; }
    }
}

// exclusive prefix over NNODES entries -> dst_base[0..NNODES]
__global__ __launch_bounds__(1024) void k_scan_dst(const int* __restrict__ cnt,
                                                   int* __restrict__ base) {
    __shared__ int ssum[1024];
    int t = threadIdx.x;
    const int CH = (NNODES + 1023) / 1024;   // 49
    int lo = t * CH, hi = min(lo + CH, NNODES);
    int s = 0;
    for (int i = lo; i < hi; i++) s += cnt[i];
    ssum[t] = s;
    __syncthreads();
    for (int off = 1; off < 1024; off <<= 1) {
        int v = (t >= off) ? ssum[t - off] : 0;
        __syncthreads();
        ssum[t] += v;
        __syncthreads();
    }
    int run = (t == 0) ? 0 : ssum[t - 1];
    for (int i = lo; i < hi; i++) { base[i] = run; run += cnt[i]; }
    if (t == 1023) base[NNODES] = run;
}

// -------- counting sort by relation + dst-rank assignment; pk = (rel<<25)|dstpos ------
__global__ void k_scatter(const int* __restrict__ rows, const int* __restrict__ cols,
                          const float* __restrict__ vals, int* __restrict__ rel_base,
                          const int* __restrict__ dst_base, int* __restrict__ dst_cur,
                          int* __restrict__ s_pk, int* __restrict__ s_src,
                          float* __restrict__ s_val) {
    __shared__ int lcnt[RREL], lbase[RREL];
    int t = threadIdx.x;
    int base = blockIdx.x * 2048;
    if (t < RREL) lcnt[t] = 0;
    __syncthreads();
    int relv[8];
#pragma unroll
    for (int i = 0; i < 8; i++) {
        int k = base + i * 256 + t;
        if (k < NNZ_) { int r = rows[k] / NNODES; relv[i] = r; atomicAdd(&lcnt[r], 1); }
        else relv[i] = -1;
    }
    __syncthreads();
    if (t < RREL) lbase[t] = atomicAdd(&rel_base[t], lcnt[t]);
    __syncthreads();
    if (t < RREL) lcnt[t] = 0;
    __syncthreads();
#pragma unroll
    for (int i = 0; i < 8; i++) {
        int k = base + i * 256 + t;
        if (k < NNZ_) {
            int r = relv[i];
            int rw = rows[k];
            int dst = rw - r * NNODES;
            int pos = lbase[r] + atomicAdd(&lcnt[r], 1);
            int p = dst_base[dst] + atomicAdd(&dst_cur[dst], 1);     // < 2^21
            __builtin_nontemporal_store((int)(((uint32)r << 25) | (uint32)p), s_pk + pos);
            __builtin_nontemporal_store(cols[k], s_src + pos);
            __builtin_nontemporal_store(vals[k], s_val + pos);
        }
    }
}

// ---------------- per-edge matvec helper ----------------
template <int FO>
__device__ __forceinline__ void matvec_acc(const float* __restrict__ wb,
                                           const float (&xr)[32], float (&acc)[FO]) {
#pragma unroll
    for (int f = 0; f < 32; f++) {
        float xf = xr[f];
#pragma unroll
        for (int e = 0; e < FO; e++) acc[e] = fmaf(xf, wb[f * FO + e], acc[e]);
    }
}

// ------- stage A: y[p] = bf16( val * (Xb[src] @ W[rel]) ), nontemporal stores --------
// input rows are always 32 features packed bf16 (16 uints = 4 u32x4)
template <int FO>
__global__ __launch_bounds__(256) void k_edgeA(const int* __restrict__ s_pk,
                                               const int* __restrict__ s_src,
                                               const float* __restrict__ s_val,
                                               const u32x4* __restrict__ Xb,
                                               const float* __restrict__ W,
                                               uint32* __restrict__ y) {
    const int UPR = FO / 2;                      // uints per out row: 16 / 8
    const int STRIDE = (FO == 32) ? 66 : 68;     // <=2-way LDS aliasing both phases (free)
    __shared__ uint32 Yt[4][UPR][STRIDE];
    __shared__ int P[4][64];
    int t = threadIdx.x;
    int lane = t & 63, wv = t >> 6;
    int k = blockIdx.x * 256 + t;
    int pk = 0, src = 0;
    float v = 0.f;
    if (k < NNZ_) {
        pk  = __builtin_nontemporal_load(s_pk + k);
        src = __builtin_nontemporal_load(s_src + k);
        v   = __builtin_nontemporal_load(s_val + k);
    }
    int rel = (int)(((uint32)pk) >> 25);
    int p = (k < NNZ_) ? (pk & 0x1FFFFFF) : -1;

    u32x4 q0 = Xb[src * 4 + 0], q1 = Xb[src * 4 + 1];
    u32x4 q2 = Xb[src * 4 + 2], q3 = Xb[src * 4 + 3];
    float xr[32];
    uint32 uu[16] = {q0.x, q0.y, q0.z, q0.w, q1.x, q1.y, q1.z, q1.w,
                     q2.x, q2.y, q2.z, q2.w, q3.x, q3.y, q3.z, q3.w};
#pragma unroll
    for (int i = 0; i < 16; i++) { xr[2 * i] = unpack_lo(uu[i]); xr[2 * i + 1] = unpack_hi(uu[i]); }

    float acc[FO];
#pragma unroll
    for (int e = 0; e < FO; e++) acc[e] = 0.f;

    int rel_u = __builtin_amdgcn_readfirstlane(rel);
    if (__all(rel == rel_u)) {
        matvec_acc<FO>(W + rel_u * (32 * FO), xr, acc);   // uniform -> scalar loads
    } else {
        matvec_acc<FO>(W + rel * (32 * FO), xr, acc);     // rel-boundary waves (rare)
    }

    // transpose via LDS (same-wave lockstep; compiler inserts lgkmcnt)
#pragma unroll
    for (int i = 0; i < UPR; i++)
        Yt[wv][i][lane] = pack_bf16x2(v * acc[2 * i], v * acc[2 * i + 1]);
    P[wv][lane] = p;

    const int PAIRS = UPR / 2;     // u32x2 chunks per row: 8 / 4
    const int EP = 64 / PAIRS;     // edges per store instruction: 8 / 16
    int u2 = lane % PAIRS, g = lane / PAIRS;
#pragma unroll
    for (int j = 0; j < PAIRS; j++) {
        int e = j * EP + g;
        int pe = P[wv][e];
        u32x2 val;
        val.x = Yt[wv][2 * u2][e];
        val.y = Yt[wv][2 * u2 + 1][e];
        if (pe >= 0)
            __builtin_nontemporal_store(val, (u32x2*)(y + (size_t)pe * UPR + 2 * u2));
    }
}

// ------- stage B: segmented sum over dst-sorted y, fused bias(+relu), uint4 reads ------
template <int FO, bool RELU, bool BF16OUT>
__global__ __launch_bounds__(256) void k_segB(const uint32* __restrict__ y,
                                              const int* __restrict__ dst_base,
                                              const float* __restrict__ bias,
                                              void* __restrict__ outp) {
    const int UPR = FO / 2;        // uints per row
    const int QL = UPR / 4;        // u32x4 chunks per row: 4 / 2
    const int RPI = 64 / QL;       // rows per iteration: 16 / 32
    int t = threadIdx.x, lane = t & 63, wv = t >> 6;
    int dst = blockIdx.x * 4 + wv;
    if (dst >= NNODES) return;
    int s = dst_base[dst], e2 = dst_base[dst + 1];
    int q = lane % QL, r = lane / QL;
    float acc[8];
#pragma unroll
    for (int j = 0; j < 8; j++) acc[j] = 0.f;
    for (int i = s + r; i < e2; i += RPI) {
        u32x4 u = __builtin_nontemporal_load((const u32x4*)(y + (size_t)i * UPR + 4 * q));
        acc[0] += unpack_lo(u.x); acc[1] += unpack_hi(u.x);
        acc[2] += unpack_lo(u.y); acc[3] += unpack_hi(u.y);
        acc[4] += unpack_lo(u.z); acc[5] += unpack_hi(u.z);
        acc[6] += unpack_lo(u.w); acc[7] += unpack_hi(u.w);
    }
#pragma unroll
    for (int off = 32; off >= QL; off >>= 1)
#pragma unroll
        for (int j = 0; j < 8; j++) acc[j] += __shfl_down(acc[j], off, 64);
    if (lane < QL) {
        float o[8];
#pragma unroll
        for (int j = 0; j < 8; j++) {
            o[j] = acc[j] + bias[8 * q + j];
            if (RELU) o[j] = fmaxf(o[j], 0.f);
        }
        if (BF16OUT) {
            u32x4 pk;
            pk.x = pack_bf16x2(o[0], o[1]); pk.y = pack_bf16x2(o[2], o[3]);
            pk.z = pack_bf16x2(o[4], o[5]); pk.w = pack_bf16x2(o[6], o[7]);
            ((u32x4*)outp)[(size_t)dst * QL + q] = pk;
        } else {
            float4* op = (float4*)outp;
            op[(size_t)dst * (FO / 4) + 2 * q]     = make_float4(o[0], o[1], o[2], o[3]);
            op[(size_t)dst * (FO / 4) + 2 * q + 1] = make_float4(o[4], o[5], o[6], o[7]);
        }
    }
}

extern "C" void kernel_launch(void* const* d_in, const int* in_sizes, int n_in,
                              void* d_out, int out_size, void* d_ws, size_t ws_size,
                              hipStream_t stream) {
    const float* features = (const float*)d_in[0];
    const float* vals     = (const float*)d_in[1];
    const float* comps1   = (const float*)d_in[2];
    const float* bases1   = (const float*)d_in[3];
    const float* bias1    = (const float*)d_in[4];
    const float* comps2   = (const float*)d_in[5];
    const float* bases2   = (const float*)d_in[6];
    const float* bias2    = (const float*)d_in[7];
    const int*   rows     = (const int*)d_in[8];
    const int*   cols     = (const int*)d_in[9];
    float* out = (float*)d_out;

    // ---- workspace layout (element offsets, 4-byte units) ----
    float* ws = (float*)d_ws;
    size_t o = 0;
    float* w1 = ws + o;          o += RREL * FIN * EDIM;     // 52224
    float* w2 = ws + o;          o += RREL * EDIM * CDIM;    // 26112
    uint32* Xb  = (uint32*)(ws + o); o += (size_t)NNODES * (FIN / 2);   // 0.8M
    uint32* h1b = (uint32*)(ws + o); o += (size_t)NNODES * (EDIM / 2);  // 0.8M
    int* s_pk  = (int*)(ws + o); o += NNZ_;
    int* s_src = (int*)(ws + o); o += NNZ_;
    float* s_val = ws + o;       o += NNZ_;
    int* rel_cnt  = (int*)(ws + o); o += RREL;
    int* rel_base = (int*)(ws + o); o += RREL;
    int* dst_cnt  = (int*)(ws + o); o += NNODES;
    int* dst_cur  = (int*)(ws + o); o += NNODES;
    int* dst_base = (int*)(ws + o); o += NNODES + 1;
    o = (o + 3) & ~(size_t)3;
    uint32* y = (uint32*)(ws + o);                           // NNZ * 16 uints, reused

    // zero the counter region (rel_cnt .. dst_cur, contiguous)
    hipMemsetAsync(rel_cnt, 0, (2 * RREL + 2 * NNODES) * sizeof(int), stream);

    k_weights<<<(RREL * FIN * EDIM + 255) / 256, 256, 0, stream>>>(comps1, bases1, comps2, bases2, w1, w2);
    k_tobf16<<<(NNODES * FIN / 2 + 255) / 256, 256, 0, stream>>>((const float2*)features, Xb, NNODES * FIN / 2);
    k_hist<<<512, 256, 0, stream>>>(rows, rel_cnt, dst_cnt);
    k_prefix<<<1, 64, 0, stream>>>(rel_cnt, rel_base);
    k_scan_dst<<<1, 1024, 0, stream>>>(dst_cnt, dst_base);
    k_scatter<<<(NNZ_ + 2047) / 2048, 256, 0, stream>>>(rows, cols, vals, rel_base, dst_base,
                                                        dst_cur, s_pk, s_src, s_val);

    k_edgeA<EDIM><<<(NNZ_ + 255) / 256, 256, 0, stream>>>(s_pk, s_src, s_val, (const u32x4*)Xb, w1, y);
    k_segB<EDIM, true, true><<<(NNODES + 3) / 4, 256, 0, stream>>>(y, dst_base, bias1, h1b);
    k_edgeA<CDIM><<<(NNZ_ + 255) / 256, 256, 0, stream>>>(s_pk, s_src, s_val, (const u32x4*)h1b, w2, y);
    k_segB<CDIM, false, false><<<(NNODES + 3) / 4, 256, 0, stream>>>(y, dst_base, bias2, out);
}

// Round 4
// 671.036 us; speedup vs baseline: 1.3879x; 1.3879x over previous
//
#include <hip/hip_runtime.h>

#define NNODES 50000
#define RREL 51
#define FIN 32
#define EDIM 32
#define CDIM 16
#define BB 30
#define NNZ_ 2000000
#define CAP_ 2001152   // ceil((NNZ_ + 51*15 + 255)/256)*256 : padded edge capacity

typedef unsigned int uint32;
typedef unsigned short ushort;
typedef uint32 u32x2 __attribute__((ext_vector_type(2)));
typedef uint32 u32x4 __attribute__((ext_vector_type(4)));
typedef short bf16x8 __attribute__((ext_vector_type(8)));
typedef float f32x4 __attribute__((ext_vector_type(4)));

// ---------- bf16 helpers (manual RNE) ----------
static __device__ __forceinline__ uint32 pack_bf16x2(float a, float b) {
    uint32 ua = __builtin_bit_cast(uint32, a);
    uint32 ub = __builtin_bit_cast(uint32, b);
    ua += 0x7fffu + ((ua >> 16) & 1u);
    ub += 0x7fffu + ((ub >> 16) & 1u);
    return (ua >> 16) | (ub & 0xffff0000u);
}
static __device__ __forceinline__ ushort bf16_1(float x) {
    uint32 u = __builtin_bit_cast(uint32, x);
    u += 0x7fffu + ((u >> 16) & 1u);
    return (ushort)(u >> 16);
}
static __device__ __forceinline__ float unpack_lo(uint32 u) { return __builtin_bit_cast(float, u << 16); }
static __device__ __forceinline__ float unpack_hi(uint32 u) { return __builtin_bit_cast(float, u & 0xffff0000u); }

// ---- weight build into MFMA-B-swizzled bf16 layout: Wb[r][kchunk][n][j] , k=8*kchunk+j ----
__global__ void k_weights(const float* __restrict__ comps1, const float* __restrict__ bases1,
                          const float* __restrict__ comps2, const float* __restrict__ bases2,
                          ushort* __restrict__ Wb1, ushort* __restrict__ Wb2) {
    int i = blockIdx.x * 256 + threadIdx.x;
    if (i < RREL * FIN * EDIM) {          // (r, f, e): f = k index, e = n index
        int r = i >> 10, fe = i & 1023, f = fe >> 5, e = fe & 31;
        float acc = 0.f;
#pragma unroll
        for (int b = 0; b < BB; b++) acc += comps1[r * BB + b] * bases1[b * 1024 + fe];
        Wb1[((r * 4 + (f >> 3)) * 32 + e) * 8 + (f & 7)] = bf16_1(acc);
    }
    if (i < RREL * EDIM * CDIM) {         // (r, k, c)
        int r = i >> 9, ec = i & 511, kk = ec >> 4, c = ec & 15;
        float acc = 0.f;
#pragma unroll
        for (int b = 0; b < BB; b++) acc += comps2[r * BB + b] * bases2[b * 512 + ec];
        Wb2[((r * 4 + (kk >> 3)) * 16 + c) * 8 + (kk & 7)] = bf16_1(acc);
    }
}

// ---------------- fp32 features -> packed bf16 rows (64 B/row, L2-resident) ----------
__global__ void k_tobf16(const float2* __restrict__ src, uint32* __restrict__ dst, int n2) {
    int i = blockIdx.x * 256 + threadIdx.x;
    if (i < n2) {
        float2 f = src[i];
        dst[i] = pack_bf16x2(f.x, f.y);
    }
}

// ---------------- histograms ----------------
__global__ void k_hist(const int* __restrict__ rows, int* __restrict__ rel_cnt,
                       int* __restrict__ dst_cnt) {
    __shared__ int lc[RREL];
    if (threadIdx.x < RREL) lc[threadIdx.x] = 0;
    __syncthreads();
    int stride = gridDim.x * blockDim.x;
    for (int k = blockIdx.x * blockDim.x + threadIdx.x; k < NNZ_; k += stride) {
        int rw = rows[k];
        int rel = rw / NNODES;
        atomicAdd(&lc[rel], 1);
        atomicAdd(&dst_cnt[rw - rel * NNODES], 1);
    }
    __syncthreads();
    if (threadIdx.x < RREL) atomicAdd(&rel_cnt[threadIdx.x], lc[threadIdx.x]);
}

// 16-aligned per-relation bases + mutable cursor copy
__global__ void k_prefix(const int* __restrict__ rel_cnt, int* __restrict__ pad_base,
                         int* __restrict__ rel_cur) {
    if (threadIdx.x == 0) {
        int acc = 0;
        for (int r = 0; r < RREL; r++) {
            pad_base[r] = acc; rel_cur[r] = acc;
            acc += (rel_cnt[r] + 15) & ~15;
        }
        pad_base[RREL] = acc;
    }
}

// fill padding gaps with dummy edges (rel = segment rel so subtiles stay rel-uniform!)
__global__ void k_padfill(const int* __restrict__ rel_cnt, const int* __restrict__ pad_base,
                          int* __restrict__ s_pk, int* __restrict__ s_src,
                          float* __restrict__ s_val) {
    int r = blockIdx.x;
    int start, end, relv;
    if (r < RREL) { start = pad_base[r] + rel_cnt[r]; end = pad_base[r + 1]; relv = r; }
    else { start = pad_base[RREL]; end = CAP_; relv = 0; }
    for (int i = start + threadIdx.x; i < end; i += 64) {
        s_pk[i] = (int)(((uint32)relv << 25) | (uint32)NNZ_);   // dummy -> scratch y row
        s_src[i] = 0;
        s_val[i] = 0.f;
    }
}

// exclusive prefix over NNODES entries -> dst_base[0..NNODES]
__global__ __launch_bounds__(1024) void k_scan_dst(const int* __restrict__ cnt,
                                                   int* __restrict__ base) {
    __shared__ int ssum[1024];
    int t = threadIdx.x;
    const int CH = (NNODES + 1023) / 1024;   // 49
    int lo = t * CH, hi = min(lo + CH, NNODES);
    int s = 0;
    for (int i = lo; i < hi; i++) s += cnt[i];
    ssum[t] = s;
    __syncthreads();
    for (int off = 1; off < 1024; off <<= 1) {
        int v = (t >= off) ? ssum[t - off] : 0;
        __syncthreads();
        ssum[t] += v;
        __syncthreads();
    }
    int run = (t == 0) ? 0 : ssum[t - 1];
    for (int i = lo; i < hi; i++) { base[i] = run; run += cnt[i]; }
    if (t == 1023) base[NNODES] = run;
}

// -------- counting sort by relation (16-aligned segments) + dst-rank; pk=(rel<<25)|pos ----
__global__ void k_scatter(const int* __restrict__ rows, const int* __restrict__ cols,
                          const float* __restrict__ vals, int* __restrict__ rel_cur,
                          const int* __restrict__ dst_base, int* __restrict__ dst_cur,
                          int* __restrict__ s_pk, int* __restrict__ s_src,
                          float* __restrict__ s_val) {
    __shared__ int lcnt[RREL], lbase[RREL];
    int t = threadIdx.x;
    int base = blockIdx.x * 2048;
    if (t < RREL) lcnt[t] = 0;
    __syncthreads();
    int relv[8];
#pragma unroll
    for (int i = 0; i < 8; i++) {
        int k = base + i * 256 + t;
        if (k < NNZ_) { int r = rows[k] / NNODES; relv[i] = r; atomicAdd(&lcnt[r], 1); }
        else relv[i] = -1;
    }
    __syncthreads();
    if (t < RREL) lbase[t] = atomicAdd(&rel_cur[t], lcnt[t]);
    __syncthreads();
    if (t < RREL) lcnt[t] = 0;
    __syncthreads();
#pragma unroll
    for (int i = 0; i < 8; i++) {
        int k = base + i * 256 + t;
        if (k < NNZ_) {
            int r = relv[i];
            int rw = rows[k];
            int dst = rw - r * NNODES;
            int pos = lbase[r] + atomicAdd(&lcnt[r], 1);
            int p = dst_base[dst] + atomicAdd(&dst_cur[dst], 1);     // < 2^21
            s_pk[pos] = (int)(((uint32)r << 25) | (uint32)p);
            s_src[pos] = cols[k];
            s_val[pos] = vals[k];
        }
    }
}

// ------- stage A (MFMA): y[p] = bf16( val * (Xb[src] @ W[rel]) ) -------------------
// A-frag gathered straight from bf16 node rows; B-frag from swizzled Wb (L1-resident).
template <int FO>
__global__ __launch_bounds__(256) void k_edgeA(const int* __restrict__ s_pk,
                                               const int* __restrict__ s_src,
                                               const float* __restrict__ s_val,
                                               const u32x4* __restrict__ Xb,
                                               const u32x4* __restrict__ Wb,
                                               uint32* __restrict__ y) {
    const int NT = FO / 16;          // N-tiles: 2 / 1
    const int CHUNKS = FO / 4;       // float4 per out row: 8 / 4
    const int TS = FO + 4;           // LDS row stride (floats): 36 / 20 -> <=2-way banks
    const int UPR = FO / 2;          // uints per out row
    const int NW = (FO == 32) ? 32 : 16;
    __shared__ float T[4][32][TS];
    __shared__ float V[4][64];
    __shared__ int P[4][64];
    int t = threadIdx.x, lane = t & 63, wv = t >> 6;
    int ln15 = lane & 15, quad = lane >> 4;
    int k0 = blockIdx.x * 256 + wv * 64;

    int pk_own = s_pk[k0 + lane];
    P[wv][lane] = pk_own & 0x1FFFFFF;
    V[wv][lane] = s_val[k0 + lane];

    f32x4 acc[4][NT];
    const f32x4 zero = {0.f, 0.f, 0.f, 0.f};
#pragma unroll
    for (int s = 0; s < 4; s++) {
        int ks = k0 + s * 16 + ln15;
        int pks = s_pk[ks];
        int srcs = s_src[ks];
        int rels = (int)(((uint32)pks) >> 25);           // uniform within 16-edge subtile
        bf16x8 a = __builtin_bit_cast(bf16x8, Xb[srcs * 4 + quad]);
#pragma unroll
        for (int tt = 0; tt < NT; tt++) {
            bf16x8 b = __builtin_bit_cast(bf16x8, Wb[(rels * 4 + quad) * NW + ln15 + 16 * tt]);
            acc[s][tt] = __builtin_amdgcn_mfma_f32_16x16x32_bf16(a, b, zero, 0, 0, 0);
        }
    }

    // epilogue: scale by val, transpose via LDS, NT-store 64B rows; 2 passes of 32 edges
#pragma unroll
    for (int p2 = 0; p2 < 2; p2++) {
#pragma unroll
        for (int si = 0; si < 2; si++) {
            int s = p2 * 2 + si;
            float4 vv = *(const float4*)&V[wv][s * 16 + quad * 4];   // rows quad*4..+3
            float vr[4] = {vv.x, vv.y, vv.z, vv.w};
#pragma unroll
            for (int tt = 0; tt < NT; tt++)
#pragma unroll
                for (int rg = 0; rg < 4; rg++)
                    T[wv][si * 16 + quad * 4 + rg][ln15 + 16 * tt] = acc[s][tt][rg] * vr[rg];
        }
        int u2 = lane % CHUNKS, g = lane / CHUNKS;
#pragma unroll
        for (int j = 0; j < CHUNKS / 2; j++) {
            int e2 = j * (64 / CHUNKS) + g;
            float4 f = *(const float4*)&T[wv][e2][u2 * 4];
            int pe = P[wv][p2 * 32 + e2];
            u32x2 val;
            val.x = pack_bf16x2(f.x, f.y);
            val.y = pack_bf16x2(f.z, f.w);
            __builtin_nontemporal_store(val, (u32x2*)(y + (size_t)pe * UPR + u2 * 2));
        }
    }
}

// ------- stage B: segmented sum over dst-sorted y, fused bias(+relu) ------
template <int FO, bool RELU, bool BF16OUT>
__global__ __launch_bounds__(256) void k_segB(const uint32* __restrict__ y,
                                              const int* __restrict__ dst_base,
                                              const float* __restrict__ bias,
                                              void* __restrict__ outp) {
    const int UPR = FO / 2;        // uints per row
    const int QL = UPR / 4;        // u32x4 chunks per row: 4 / 2
    const int RPI = 64 / QL;       // rows per iteration: 16 / 32
    int t = threadIdx.x, lane = t & 63, wv = t >> 6;
    int dst = blockIdx.x * 4 + wv;
    if (dst >= NNODES) return;
    int s = dst_base[dst], e2 = dst_base[dst + 1];
    int q = lane % QL, r = lane / QL;
    float acc[8];
#pragma unroll
    for (int j = 0; j < 8; j++) acc[j] = 0.f;
    for (int i = s + r; i < e2; i += RPI) {
        u32x4 u = __builtin_nontemporal_load((const u32x4*)(y + (size_t)i * UPR + 4 * q));
        acc[0] += unpack_lo(u.x); acc[1] += unpack_hi(u.x);
        acc[2] += unpack_lo(u.y); acc[3] += unpack_hi(u.y);
        acc[4] += unpack_lo(u.z); acc[5] += unpack_hi(u.z);
        acc[6] += unpack_lo(u.w); acc[7] += unpack_hi(u.w);
    }
#pragma unroll
    for (int off = 32; off >= QL; off >>= 1)
#pragma unroll
        for (int j = 0; j < 8; j++) acc[j] += __shfl_down(acc[j], off, 64);
    if (lane < QL) {
        float o[8];
#pragma unroll
        for (int j = 0; j < 8; j++) {
            o[j] = acc[j] + bias[8 * q + j];
            if (RELU) o[j] = fmaxf(o[j], 0.f);
        }
        if (BF16OUT) {
            u32x4 pk;
            pk.x = pack_bf16x2(o[0], o[1]); pk.y = pack_bf16x2(o[2], o[3]);
            pk.z = pack_bf16x2(o[4], o[5]); pk.w = pack_bf16x2(o[6], o[7]);
            ((u32x4*)outp)[(size_t)dst * QL + q] = pk;
        } else {
            float4* op = (float4*)outp;
            op[(size_t)dst * (FO / 4) + 2 * q]     = make_float4(o[0], o[1], o[2], o[3]);
            op[(size_t)dst * (FO / 4) + 2 * q + 1] = make_float4(o[4], o[5], o[6], o[7]);
        }
    }
}

extern "C" void kernel_launch(void* const* d_in, const int* in_sizes, int n_in,
                              void* d_out, int out_size, void* d_ws, size_t ws_size,
                              hipStream_t stream) {
    const float* features = (const float*)d_in[0];
    const float* vals     = (const float*)d_in[1];
    const float* comps1   = (const float*)d_in[2];
    const float* bases1   = (const float*)d_in[3];
    const float* bias1    = (const float*)d_in[4];
    const float* comps2   = (const float*)d_in[5];
    const float* bases2   = (const float*)d_in[6];
    const float* bias2    = (const float*)d_in[7];
    const int*   rows     = (const int*)d_in[8];
    const int*   cols     = (const int*)d_in[9];
    float* out = (float*)d_out;

    // ---- workspace layout (4-byte element offsets) ----
    float* ws = (float*)d_ws;
    size_t o = 0;
    ushort* Wb1 = (ushort*)(ws + o); o += RREL * FIN * EDIM / 2;   // 26112 uints
    ushort* Wb2 = (ushort*)(ws + o); o += RREL * EDIM * CDIM / 2;  // 13056
    uint32* Xb  = (uint32*)(ws + o); o += (size_t)NNODES * (FIN / 2);   // 0.8M
    uint32* h1b = (uint32*)(ws + o); o += (size_t)NNODES * (EDIM / 2);  // 0.8M
    int* s_pk  = (int*)(ws + o); o += CAP_;
    int* s_src = (int*)(ws + o); o += CAP_;
    float* s_val = ws + o;       o += CAP_;
    int* rel_cnt  = (int*)(ws + o); o += RREL;        // | zeroed together
    int* dst_cnt  = (int*)(ws + o); o += NNODES;      // |
    int* dst_cur  = (int*)(ws + o); o += NNODES;      // |
    int* rel_cur  = (int*)(ws + o); o += RREL;
    int* pad_base = (int*)(ws + o); o += RREL + 1;
    int* dst_base = (int*)(ws + o); o += NNODES + 1;
    o = (o + 3) & ~(size_t)3;
    uint32* y = (uint32*)(ws + o);     // (NNZ_+1) rows x 16 uints, reused both layers

    hipMemsetAsync(rel_cnt, 0, (RREL + 2 * NNODES) * sizeof(int), stream);

    k_weights<<<(RREL * FIN * EDIM + 255) / 256, 256, 0, stream>>>(comps1, bases1, comps2, bases2, Wb1, Wb2);
    k_tobf16<<<(NNODES * FIN / 2 + 255) / 256, 256, 0, stream>>>((const float2*)features, Xb, NNODES * FIN / 2);
    k_hist<<<512, 256, 0, stream>>>(rows, rel_cnt, dst_cnt);
    k_prefix<<<1, 64, 0, stream>>>(rel_cnt, pad_base, rel_cur);
    k_scan_dst<<<1, 1024, 0, stream>>>(dst_cnt, dst_base);
    k_padfill<<<RREL + 1, 64, 0, stream>>>(rel_cnt, pad_base, s_pk, s_src, s_val);
    k_scatter<<<(NNZ_ + 2047) / 2048, 256, 0, stream>>>(rows, cols, vals, rel_cur, dst_base,
                                                        dst_cur, s_pk, s_src, s_val);

    k_edgeA<EDIM><<<CAP_ / 256, 256, 0, stream>>>(s_pk, s_src, s_val, (const u32x4*)Xb,
                                                  (const u32x4*)Wb1, y);
    k_segB<EDIM, true, true><<<(NNODES + 3) / 4, 256, 0, stream>>>(y, dst_base, bias1, h1b);
    k_edgeA<CDIM><<<CAP_ / 256, 256, 0, stream>>>(s_pk, s_src, s_val, (const u32x4*)h1b,
                                                  (const u32x4*)Wb2, y);
    k_segB<CDIM, false, false><<<(NNODES + 3) / 4, 256, 0, stream>>>(y, dst_base, bias2, out);
}

// Round 5
// 477.550 us; speedup vs baseline: 1.9502x; 1.4052x over previous
//
#include <hip/hip_runtime.h>

#define NNODES 50000
#define RREL 51
#define FIN 32
#define EDIM 32
#define CDIM 16
#define BB 30
#define NNZ_ 2000000
#define CAP_ 2000896   // ceil((NNZ_ + 51*15)/512)*512 : padded edge capacity
#define EPB 4096       // edges per block in hist/scatter

typedef unsigned int uint32;
typedef unsigned short ushort;
typedef uint32 u32x2 __attribute__((ext_vector_type(2)));
typedef uint32 u32x4 __attribute__((ext_vector_type(4)));
typedef short bf16x8 __attribute__((ext_vector_type(8)));
typedef float f32x4 __attribute__((ext_vector_type(4)));

// ---------- bf16 helpers (manual RNE) ----------
static __device__ __forceinline__ uint32 pack_bf16x2(float a, float b) {
    uint32 ua = __builtin_bit_cast(uint32, a);
    uint32 ub = __builtin_bit_cast(uint32, b);
    ua += 0x7fffu + ((ua >> 16) & 1u);
    ub += 0x7fffu + ((ub >> 16) & 1u);
    return (ua >> 16) | (ub & 0xffff0000u);
}
static __device__ __forceinline__ ushort bf16_1(float x) {
    uint32 u = __builtin_bit_cast(uint32, x);
    u += 0x7fffu + ((u >> 16) & 1u);
    return (ushort)(u >> 16);
}
static __device__ __forceinline__ float unpack_lo(uint32 u) { return __builtin_bit_cast(float, u << 16); }
static __device__ __forceinline__ float unpack_hi(uint32 u) { return __builtin_bit_cast(float, u & 0xffff0000u); }

// ---- weight build into MFMA-B-swizzled bf16 layout: Wb[r][kchunk][n][j], k=8*kchunk+j ----
__global__ void k_weights(const float* __restrict__ comps1, const float* __restrict__ bases1,
                          const float* __restrict__ comps2, const float* __restrict__ bases2,
                          ushort* __restrict__ Wb1, ushort* __restrict__ Wb2) {
    int i = blockIdx.x * 256 + threadIdx.x;
    if (i < RREL * FIN * EDIM) {          // (r, f, e): f = k index, e = n index
        int r = i >> 10, fe = i & 1023, f = fe >> 5, e = fe & 31;
        float acc = 0.f;
#pragma unroll
        for (int b = 0; b < BB; b++) acc += comps1[r * BB + b] * bases1[b * 1024 + fe];
        Wb1[((r * 4 + (f >> 3)) * 32 + e) * 8 + (f & 7)] = bf16_1(acc);
    }
    if (i < RREL * EDIM * CDIM) {         // (r, k, c)
        int r = i >> 9, ec = i & 511, kk = ec >> 4, c = ec & 15;
        float acc = 0.f;
#pragma unroll
        for (int b = 0; b < BB; b++) acc += comps2[r * BB + b] * bases2[b * 512 + ec];
        Wb2[((r * 4 + (kk >> 3)) * 16 + c) * 8 + (kk & 7)] = bf16_1(acc);
    }
}

// ---------------- fp32 features -> packed bf16 rows (64 B/row, L2-resident) ----------
__global__ void k_tobf16(const float2* __restrict__ src, uint32* __restrict__ dst, int n2) {
    int i = blockIdx.x * 256 + threadIdx.x;
    if (i < n2) {
        float2 f = src[i];
        dst[i] = pack_bf16x2(f.x, f.y);
    }
}

// ---------------- histograms (int4 reads, 16 edges/thread) ----------------
__global__ __launch_bounds__(256) void k_hist(const int* __restrict__ rows,
                                              int* __restrict__ rel_cnt,
                                              int* __restrict__ dst_cnt) {
    __shared__ int lc[RREL];
    int t = threadIdx.x;
    if (t < RREL) lc[t] = 0;
    __syncthreads();
    size_t base = (size_t)blockIdx.x * EPB;
#pragma unroll
    for (int i = 0; i < 4; i++) {
        size_t k = base + (size_t)t * 16 + i * 4;
        int rr[4];
        if (k + 4 <= NNZ_) {
            int4 rw = *(const int4*)(rows + k);
            rr[0] = rw.x; rr[1] = rw.y; rr[2] = rw.z; rr[3] = rw.w;
        } else {
#pragma unroll
            for (int j = 0; j < 4; j++) rr[j] = (k + j < NNZ_) ? rows[k + j] : -1;
        }
#pragma unroll
        for (int j = 0; j < 4; j++) {
            if (rr[j] >= 0) {
                int rel = rr[j] / NNODES;
                atomicAdd(&lc[rel], 1);
                atomicAdd(&dst_cnt[rr[j] - rel * NNODES], 1);
            }
        }
    }
    __syncthreads();
    if (t < RREL) atomicAdd(&rel_cnt[t], lc[t]);
}

// ---- single-block scan: dst_cnt -> dst_base[0..N], plus fused rel prefix (16-aligned) ----
__global__ __launch_bounds__(1024) void k_scan(const int* __restrict__ cnt, int* __restrict__ base,
                                               const int* __restrict__ rel_cnt,
                                               int* __restrict__ pad_base, int* __restrict__ rel_cur) {
    __shared__ int ssum[1024];
    int t = threadIdx.x;
    const int CH = 52;                 // 13 int4s per thread; 1024*52 >= NNODES
    int lo = t * CH;
    int s = 0;
#pragma unroll
    for (int c = 0; c < 13; c++) {
        int i = lo + c * 4;
        if (i + 4 <= NNODES) {
            int4 q = *(const int4*)(cnt + i);
            s += q.x + q.y + q.z + q.w;
        } else {
            for (int j = 0; j < 4; j++) if (i + j < NNODES) s += cnt[i + j];
        }
    }
    ssum[t] = s;
    if (t == 0) {                      // fused rel prefix (others proceed to barrier)
        int a = 0;
        for (int r = 0; r < RREL; r++) {
            pad_base[r] = a; rel_cur[r] = a;
            a += (rel_cnt[r] + 15) & ~15;
        }
        pad_base[RREL] = a;
    }
    __syncthreads();
    for (int off = 1; off < 1024; off <<= 1) {
        int u = (t >= off) ? ssum[t - off] : 0;
        __syncthreads();
        ssum[t] += u;
        __syncthreads();
    }
    int run = (t == 0) ? 0 : ssum[t - 1];
#pragma unroll
    for (int c = 0; c < 13; c++) {
        int i = lo + c * 4;
        if (i + 4 <= NNODES) {
            int4 q = *(const int4*)(cnt + i);
            int4 w;
            w.x = run; run += q.x; w.y = run; run += q.y;
            w.z = run; run += q.z; w.w = run; run += q.w;
            *(int4*)(base + i) = w;
        } else {
            for (int j = 0; j < 4; j++) if (i + j < NNODES) { base[i + j] = run; run += cnt[i + j]; }
        }
    }
    if (t == 1023) base[NNODES] = run;
}

// fill padding gaps with dummy edges (rel = segment rel so subtiles stay rel-uniform)
__global__ void k_padfill(const int* __restrict__ rel_cnt, const int* __restrict__ pad_base,
                          int* __restrict__ s_pk, int* __restrict__ s_src,
                          float* __restrict__ s_val) {
    int r = blockIdx.x;
    int start, end, relv;
    if (r < RREL) { start = pad_base[r] + rel_cnt[r]; end = pad_base[r + 1]; relv = r; }
    else { start = pad_base[RREL]; end = CAP_; relv = 0; }
    for (int i = start + threadIdx.x; i < end; i += 64) {
        s_pk[i] = (int)(((uint32)relv << 25) | (uint32)NNZ_);   // dummy -> scratch y row
        s_src[i] = 0;
        s_val[i] = 0.f;
    }
}

// ------ LDS-binned counting sort by relation + dst-rank; coalesced bucket copy-out ------
__global__ __launch_bounds__(256) void k_scatter(const int* __restrict__ rows, const int* __restrict__ cols,
                                                 const float* __restrict__ vals, int* __restrict__ rel_cur,
                                                 const int* __restrict__ dst_base, int* __restrict__ dst_cur,
                                                 int* __restrict__ s_pk, int* __restrict__ s_src,
                                                 float* __restrict__ s_val) {
    __shared__ int lcnt[RREL], lbase[RREL], gbase[RREL];
    __shared__ int st_pk[EPB];
    __shared__ int st_src[EPB];
    __shared__ float st_val[EPB];
    int t = threadIdx.x;
    size_t base = (size_t)blockIdx.x * EPB;
    if (t < RREL) lcnt[t] = 0;
    __syncthreads();
    int relv[16], dstv[16];
#pragma unroll
    for (int i = 0; i < 4; i++) {
        size_t k = base + (size_t)t * 16 + i * 4;
        int rr[4];
        if (k + 4 <= NNZ_) {
            int4 rw = *(const int4*)(rows + k);
            rr[0] = rw.x; rr[1] = rw.y; rr[2] = rw.z; rr[3] = rw.w;
        } else {
#pragma unroll
            for (int j = 0; j < 4; j++) rr[j] = (k + j < NNZ_) ? rows[k + j] : -1;
        }
#pragma unroll
        for (int j = 0; j < 4; j++) {
            if (rr[j] >= 0) {
                int rel = rr[j] / NNODES;
                relv[i * 4 + j] = rel;
                dstv[i * 4 + j] = rr[j] - rel * NNODES;
                atomicAdd(&lcnt[rel], 1);
            } else relv[i * 4 + j] = -1;
        }
    }
    __syncthreads();
    if (t < 64) {                       // wave-0 scan of 51 bucket counts + global reserve
        int v = (t < RREL) ? lcnt[t] : 0;
        int sum = v;
#pragma unroll
        for (int off = 1; off < 64; off <<= 1) {
            int u = __shfl_up(sum, off, 64);
            if (t >= off) sum += u;
        }
        if (t < RREL) { lbase[t] = sum - v; gbase[t] = atomicAdd(&rel_cur[t], v); }
    }
    __syncthreads();
    if (t < RREL) lcnt[t] = 0;
    __syncthreads();
#pragma unroll
    for (int i = 0; i < 4; i++) {
        size_t k = base + (size_t)t * 16 + i * 4;
        int cc[4]; float vv[4];
        if (k + 4 <= NNZ_) {
            int4 cw = *(const int4*)(cols + k);
            float4 vw = *(const float4*)(vals + k);
            cc[0] = cw.x; cc[1] = cw.y; cc[2] = cw.z; cc[3] = cw.w;
            vv[0] = vw.x; vv[1] = vw.y; vv[2] = vw.z; vv[3] = vw.w;
        } else {
#pragma unroll
            for (int j = 0; j < 4; j++) {
                cc[j] = (k + j < NNZ_) ? cols[k + j] : 0;
                vv[j] = (k + j < NNZ_) ? vals[k + j] : 0.f;
            }
        }
#pragma unroll
        for (int j = 0; j < 4; j++) {
            int rel = relv[i * 4 + j];
            if (rel >= 0) {
                int slot = lbase[rel] + atomicAdd(&lcnt[rel], 1);
                int dst = dstv[i * 4 + j];
                int p = dst_base[dst] + atomicAdd(&dst_cur[dst], 1);   // < 2^21
                st_pk[slot] = (int)(((uint32)rel << 25) | (uint32)p);
                st_src[slot] = cc[j];
                st_val[slot] = vv[j];
            }
        }
    }
    __syncthreads();
    for (int b = 0; b < RREL; b++) {    // coalesced per-bucket copy-out
        int len = lcnt[b], lb = lbase[b], gb = gbase[b];
        for (int i2 = t; i2 < len; i2 += 256) {
            s_pk[gb + i2] = st_pk[lb + i2];
            s_src[gb + i2] = st_src[lb + i2];
            s_val[gb + i2] = st_val[lb + i2];
        }
    }
}

// ------- stage A (MFMA): y[p] = bf16( val * (Xb[src] @ W[rel]) ), 128 edges/wave -------
template <int FO>
__global__ __launch_bounds__(256) void k_edgeA(const int* __restrict__ s_pk,
                                               const int* __restrict__ s_src,
                                               const float* __restrict__ s_val,
                                               const u32x4* __restrict__ Xb,
                                               const u32x4* __restrict__ Wb,
                                               uint32* __restrict__ y) {
    const int NT = FO / 16;          // N-tiles: 2 / 1
    const int UPR = FO / 2;          // uints per out row: 16 / 8
    const int NW = (FO == 32) ? 32 : 16;
    const int TS = FO + 4;           // LDS row stride (floats)
    __shared__ float T[4][32][TS];
    __shared__ float V[4][128];
    __shared__ int P[4][128];
    int t = threadIdx.x, lane = t & 63, wv = t >> 6;
    int ln15 = lane & 15, quad = lane >> 4;
    size_t k0 = (size_t)blockIdx.x * 512 + wv * 128;

    int pk0 = s_pk[k0 + lane],      pk1 = s_pk[k0 + 64 + lane];
    int sc0 = s_src[k0 + lane],     sc1 = s_src[k0 + 64 + lane];
    V[wv][lane] = s_val[k0 + lane]; V[wv][64 + lane] = s_val[k0 + 64 + lane];
    P[wv][lane] = pk0 & 0x1FFFFFF;  P[wv][64 + lane] = pk1 & 0x1FFFFFF;

    f32x4 acc[8][NT];
    const f32x4 zero = {0.f, 0.f, 0.f, 0.f};
#pragma unroll
    for (int s = 0; s < 8; s++) {
        int opk = (s < 4) ? pk0 : pk1;
        int osc = (s < 4) ? sc0 : sc1;
        int srcs = __shfl(osc, (s & 3) * 16 + ln15, 64);
        int rels = (int)(((uint32)__builtin_amdgcn_readfirstlane(__shfl(opk, (s & 3) * 16, 64))) >> 25);
        bf16x8 a = __builtin_bit_cast(bf16x8, Xb[(size_t)srcs * 4 + quad]);
#pragma unroll
        for (int tt = 0; tt < NT; tt++) {
            bf16x8 b = __builtin_bit_cast(bf16x8, Wb[(rels * 4 + quad) * NW + ln15 + 16 * tt]);
            acc[s][tt] = __builtin_amdgcn_mfma_f32_16x16x32_bf16(a, b, zero, 0, 0, 0);
        }
    }

    // epilogue: 4 passes of 32 edges; scale by val, LDS transpose, 16 B plain stores
#pragma unroll
    for (int p2 = 0; p2 < 4; p2++) {
#pragma unroll
        for (int si = 0; si < 2; si++) {
            int s = p2 * 2 + si;
            float4 vv = *(const float4*)&V[wv][s * 16 + quad * 4];
            float vr[4] = {vv.x, vv.y, vv.z, vv.w};
#pragma unroll
            for (int tt = 0; tt < NT; tt++)
#pragma unroll
                for (int rg = 0; rg < 4; rg++)
                    T[wv][si * 16 + quad * 4 + rg][ln15 + 16 * tt] = acc[s][tt][rg] * vr[rg];
        }
        // wave-local LDS: no barrier needed (compiler orders ds ops per wave)
        if (FO == 32) {
#pragma unroll
            for (int j = 0; j < 2; j++) {
                int e2 = j * 16 + (lane >> 2), c4 = lane & 3;
                float4 f0 = *(const float4*)&T[wv][e2][c4 * 8];
                float4 f1 = *(const float4*)&T[wv][e2][c4 * 8 + 4];
                u32x4 val;
                val.x = pack_bf16x2(f0.x, f0.y); val.y = pack_bf16x2(f0.z, f0.w);
                val.z = pack_bf16x2(f1.x, f1.y); val.w = pack_bf16x2(f1.z, f1.w);
                int pe = P[wv][p2 * 32 + e2];
                *(u32x4*)(y + (size_t)pe * UPR + c4 * 4) = val;
            }
        } else {
            int e2 = lane >> 1, c4 = lane & 1;
            float4 f0 = *(const float4*)&T[wv][e2][c4 * 8];
            float4 f1 = *(const float4*)&T[wv][e2][c4 * 8 + 4];
            u32x4 val;
            val.x = pack_bf16x2(f0.x, f0.y); val.y = pack_bf16x2(f0.z, f0.w);
            val.z = pack_bf16x2(f1.x, f1.y); val.w = pack_bf16x2(f1.z, f1.w);
            int pe = P[wv][p2 * 32 + e2];
            *(u32x4*)(y + (size_t)pe * UPR + c4 * 4) = val;
        }
    }
}

// ------- stage B: segmented sum over dst-sorted y, fused bias(+relu) ------
template <int FO, bool RELU, bool BF16OUT>
__global__ __launch_bounds__(256) void k_segB(const uint32* __restrict__ y,
                                              const int* __restrict__ dst_base,
                                              const float* __restrict__ bias,
                                              void* __restrict__ outp) {
    const int UPR = FO / 2;        // uints per row
    const int QL = UPR / 4;        // u32x4 chunks per row: 4 / 2
    const int RPI = 64 / QL;       // rows per iteration: 16 / 32
    int t = threadIdx.x, lane = t & 63, wv = t >> 6;
    int dst = blockIdx.x * 4 + wv;
    if (dst >= NNODES) return;
    int s = dst_base[dst], e2 = dst_base[dst + 1];
    int q = lane % QL, r = lane / QL;
    float acc[8];
#pragma unroll
    for (int j = 0; j < 8; j++) acc[j] = 0.f;
    for (int i = s + r; i < e2; i += RPI) {
        u32x4 u = __builtin_nontemporal_load((const u32x4*)(y + (size_t)i * UPR + 4 * q));
        acc[0] += unpack_lo(u.x); acc[1] += unpack_hi(u.x);
        acc[2] += unpack_lo(u.y); acc[3] += unpack_hi(u.y);
        acc[4] += unpack_lo(u.z); acc[5] += unpack_hi(u.z);
        acc[6] += unpack_lo(u.w); acc[7] += unpack_hi(u.w);
    }
#pragma unroll
    for (int off = 32; off >= QL; off >>= 1)
#pragma unroll
        for (int j = 0; j < 8; j++) acc[j] += __shfl_down(acc[j], off, 64);
    if (lane < QL) {
        float o[8];
#pragma unroll
        for (int j = 0; j < 8; j++) {
            o[j] = acc[j] + bias[8 * q + j];
            if (RELU) o[j] = fmaxf(o[j], 0.f);
        }
        if (BF16OUT) {
            u32x4 pk;
            pk.x = pack_bf16x2(o[0], o[1]); pk.y = pack_bf16x2(o[2], o[3]);
            pk.z = pack_bf16x2(o[4], o[5]); pk.w = pack_bf16x2(o[6], o[7]);
            ((u32x4*)outp)[(size_t)dst * QL + q] = pk;
        } else {
            float4* op = (float4*)outp;
            op[(size_t)dst * (FO / 4) + 2 * q]     = make_float4(o[0], o[1], o[2], o[3]);
            op[(size_t)dst * (FO / 4) + 2 * q + 1] = make_float4(o[4], o[5], o[6], o[7]);
        }
    }
}

extern "C" void kernel_launch(void* const* d_in, const int* in_sizes, int n_in,
                              void* d_out, int out_size, void* d_ws, size_t ws_size,
                              hipStream_t stream) {
    const float* features = (const float*)d_in[0];
    const float* vals     = (const float*)d_in[1];
    const float* comps1   = (const float*)d_in[2];
    const float* bases1   = (const float*)d_in[3];
    const float* bias1    = (const float*)d_in[4];
    const float* comps2   = (const float*)d_in[5];
    const float* bases2   = (const float*)d_in[6];
    const float* bias2    = (const float*)d_in[7];
    const int*   rows     = (const int*)d_in[8];
    const int*   cols     = (const int*)d_in[9];
    float* out = (float*)d_out;

    // ---- workspace layout (4-byte element offsets; all blocks 16 B-aligned) ----
    float* ws = (float*)d_ws;
    size_t o = 0;
    ushort* Wb1 = (ushort*)(ws + o); o += RREL * FIN * EDIM / 2;        // 26112
    ushort* Wb2 = (ushort*)(ws + o); o += RREL * EDIM * CDIM / 2;       // 13056
    o = (o + 3) & ~(size_t)3;
    uint32* Xb  = (uint32*)(ws + o); o += (size_t)NNODES * (FIN / 2);   // 0.8M
    uint32* h1b = (uint32*)(ws + o); o += (size_t)NNODES * (EDIM / 2);  // 0.8M
    int* s_pk  = (int*)(ws + o); o += CAP_;
    int* s_src = (int*)(ws + o); o += CAP_;
    float* s_val = ws + o;       o += CAP_;
    // contiguous zero region: rel_cnt, pad, dst_cnt, dst_cur
    int* rel_cnt  = (int*)(ws + o); o += RREL + 1;
    int* dst_cnt  = (int*)(ws + o); o += NNODES;
    int* dst_cur  = (int*)(ws + o); o += NNODES;
    int* rel_cur  = (int*)(ws + o); o += RREL;
    int* pad_base = (int*)(ws + o); o += RREL + 1;
    o = (o + 3) & ~(size_t)3;
    int* dst_base = (int*)(ws + o); o += NNODES + 4;
    o = (o + 3) & ~(size_t)3;
    uint32* y = (uint32*)(ws + o);     // (NNZ_+1) rows x 16 uints, reused both layers

    const int NB = (NNZ_ + EPB - 1) / EPB;   // 489

    hipMemsetAsync(rel_cnt, 0, (RREL + 1 + 2 * NNODES) * sizeof(int), stream);

    k_weights<<<(RREL * FIN * EDIM + 255) / 256, 256, 0, stream>>>(comps1, bases1, comps2, bases2, Wb1, Wb2);
    k_tobf16<<<(NNODES * FIN / 2 + 255) / 256, 256, 0, stream>>>((const float2*)features, Xb, NNODES * FIN / 2);
    k_hist<<<NB, 256, 0, stream>>>(rows, rel_cnt, dst_cnt);
    k_scan<<<1, 1024, 0, stream>>>(dst_cnt, dst_base, rel_cnt, pad_base, rel_cur);
    k_padfill<<<RREL + 1, 64, 0, stream>>>(rel_cnt, pad_base, s_pk, s_src, s_val);
    k_scatter<<<NB, 256, 0, stream>>>(rows, cols, vals, rel_cur, dst_base, dst_cur,
                                      s_pk, s_src, s_val);

    k_edgeA<EDIM><<<CAP_ / 512, 256, 0, stream>>>(s_pk, s_src, s_val, (const u32x4*)Xb,
                                                  (const u32x4*)Wb1, y);
    k_segB<EDIM, true, true><<<(NNODES + 3) / 4, 256, 0, stream>>>(y, dst_base, bias1, h1b);
    k_edgeA<CDIM><<<CAP_ / 512, 256, 0, stream>>>(s_pk, s_src, s_val, (const u32x4*)h1b,
                                                  (const u32x4*)Wb2, y);
    k_segB<CDIM, false, false><<<(NNODES + 3) / 4, 256, 0, stream>>>(y, dst_base, bias2, out);
}

// Round 6
// 463.532 us; speedup vs baseline: 2.0091x; 1.0302x over previous
//
#include <hip/hip_runtime.h>

#define NNODES 50000
#define RREL 51
#define FIN 32
#define EDIM 32
#define CDIM 16
#define BB 30
#define NNZ_ 2000000
#define CAP_ 2000896   // ceil((NNZ_ + 51*15)/512)*512 : padded edge capacity
#define EPB 4096       // edges per block in hist/scatter

typedef unsigned int uint32;
typedef unsigned short ushort;
typedef uint32 u32x2 __attribute__((ext_vector_type(2)));
typedef uint32 u32x4 __attribute__((ext_vector_type(4)));
typedef short bf16x8 __attribute__((ext_vector_type(8)));
typedef float f32x4 __attribute__((ext_vector_type(4)));

// ---------- bf16 helpers (manual RNE) ----------
static __device__ __forceinline__ uint32 pack_bf16x2(float a, float b) {
    uint32 ua = __builtin_bit_cast(uint32, a);
    uint32 ub = __builtin_bit_cast(uint32, b);
    ua += 0x7fffu + ((ua >> 16) & 1u);
    ub += 0x7fffu + ((ub >> 16) & 1u);
    return (ua >> 16) | (ub & 0xffff0000u);
}
static __device__ __forceinline__ ushort bf16_1(float x) {
    uint32 u = __builtin_bit_cast(uint32, x);
    u += 0x7fffu + ((u >> 16) & 1u);
    return (ushort)(u >> 16);
}
static __device__ __forceinline__ float unpack_lo(uint32 u) { return __builtin_bit_cast(float, u << 16); }
static __device__ __forceinline__ float unpack_hi(uint32 u) { return __builtin_bit_cast(float, u & 0xffff0000u); }

// ---- weight build into MFMA-B-swizzled bf16 layout: Wb[r][kchunk][n][j], k=8*kchunk+j ----
__global__ void k_weights(const float* __restrict__ comps1, const float* __restrict__ bases1,
                          const float* __restrict__ comps2, const float* __restrict__ bases2,
                          ushort* __restrict__ Wb1, ushort* __restrict__ Wb2) {
    int i = blockIdx.x * 256 + threadIdx.x;
    if (i < RREL * FIN * EDIM) {          // (r, f, e): f = k index, e = n index
        int r = i >> 10, fe = i & 1023, f = fe >> 5, e = fe & 31;
        float acc = 0.f;
#pragma unroll
        for (int b = 0; b < BB; b++) acc += comps1[r * BB + b] * bases1[b * 1024 + fe];
        Wb1[((r * 4 + (f >> 3)) * 32 + e) * 8 + (f & 7)] = bf16_1(acc);
    }
    if (i < RREL * EDIM * CDIM) {         // (r, k, c)
        int r = i >> 9, ec = i & 511, kk = ec >> 4, c = ec & 15;
        float acc = 0.f;
#pragma unroll
        for (int b = 0; b < BB; b++) acc += comps2[r * BB + b] * bases2[b * 512 + ec];
        Wb2[((r * 4 + (kk >> 3)) * 16 + c) * 8 + (kk & 7)] = bf16_1(acc);
    }
}

// ---------------- fp32 features -> packed bf16 rows (64 B/row, L2-resident) ----------
__global__ void k_tobf16(const float2* __restrict__ src, uint32* __restrict__ dst, int n2) {
    int i = blockIdx.x * 256 + threadIdx.x;
    if (i < n2) {
        float2 f = src[i];
        dst[i] = pack_bf16x2(f.x, f.y);
    }
}

// ---------------- histograms (int4 reads, 16 edges/thread) ----------------
__global__ __launch_bounds__(256) void k_hist(const int* __restrict__ rows,
                                              int* __restrict__ rel_cnt,
                                              int* __restrict__ dst_cnt) {
    __shared__ int lc[RREL];
    int t = threadIdx.x;
    if (t < RREL) lc[t] = 0;
    __syncthreads();
    size_t base = (size_t)blockIdx.x * EPB;
#pragma unroll
    for (int i = 0; i < 4; i++) {
        size_t k = base + (size_t)t * 16 + i * 4;
        int rr[4];
        if (k + 4 <= NNZ_) {
            int4 rw = *(const int4*)(rows + k);
            rr[0] = rw.x; rr[1] = rw.y; rr[2] = rw.z; rr[3] = rw.w;
        } else {
#pragma unroll
            for (int j = 0; j < 4; j++) rr[j] = (k + j < NNZ_) ? rows[k + j] : -1;
        }
#pragma unroll
        for (int j = 0; j < 4; j++) {
            if (rr[j] >= 0) {
                int rel = rr[j] / NNODES;
                atomicAdd(&lc[rel], 1);
                atomicAdd(&dst_cnt[rr[j] - rel * NNODES], 1);
            }
        }
    }
    __syncthreads();
    if (t < RREL) atomicAdd(&rel_cnt[t], lc[t]);
}

// ---- single-block scan: dst_cnt -> dst_base AND dst_cur (cursor starts at base);
// ---- fused 16-aligned rel prefix ----
__global__ __launch_bounds__(1024) void k_scan(const int* __restrict__ cnt, int* __restrict__ base,
                                               int* __restrict__ cur,
                                               const int* __restrict__ rel_cnt,
                                               int* __restrict__ pad_base, int* __restrict__ rel_cur) {
    __shared__ int ssum[1024];
    int t = threadIdx.x;
    const int CH = 52;                 // 13 int4s per thread; 1024*52 >= NNODES
    int lo = t * CH;
    int s = 0;
#pragma unroll
    for (int c = 0; c < 13; c++) {
        int i = lo + c * 4;
        if (i + 4 <= NNODES) {
            int4 q = *(const int4*)(cnt + i);
            s += q.x + q.y + q.z + q.w;
        } else {
            for (int j = 0; j < 4; j++) if (i + j < NNODES) s += cnt[i + j];
        }
    }
    ssum[t] = s;
    if (t == 0) {                      // fused rel prefix (others proceed to barrier)
        int a = 0;
        for (int r = 0; r < RREL; r++) {
            pad_base[r] = a; rel_cur[r] = a;
            a += (rel_cnt[r] + 15) & ~15;
        }
        pad_base[RREL] = a;
    }
    __syncthreads();
    for (int off = 1; off < 1024; off <<= 1) {
        int u = (t >= off) ? ssum[t - off] : 0;
        __syncthreads();
        ssum[t] += u;
        __syncthreads();
    }
    int run = (t == 0) ? 0 : ssum[t - 1];
#pragma unroll
    for (int c = 0; c < 13; c++) {
        int i = lo + c * 4;
        if (i + 4 <= NNODES) {
            int4 q = *(const int4*)(cnt + i);
            int4 w;
            w.x = run; run += q.x; w.y = run; run += q.y;
            w.z = run; run += q.z; w.w = run; run += q.w;
            *(int4*)(base + i) = w;
            *(int4*)(cur + i) = w;
        } else {
            for (int j = 0; j < 4; j++) if (i + j < NNODES) {
                base[i + j] = run; cur[i + j] = run; run += cnt[i + j];
            }
        }
    }
    if (t == 1023) base[NNODES] = run;
}

// fill padding gaps with dummy edges (rel = segment rel so subtiles stay rel-uniform)
__global__ void k_padfill(const int* __restrict__ rel_cnt, const int* __restrict__ pad_base,
                          int* __restrict__ s_pk, int* __restrict__ s_src,
                          float* __restrict__ s_val) {
    int r = blockIdx.x;
    int start, end, relv;
    if (r < RREL) { start = pad_base[r] + rel_cnt[r]; end = pad_base[r + 1]; relv = r; }
    else { start = pad_base[RREL]; end = CAP_; relv = 0; }
    for (int i = start + threadIdx.x; i < end; i += 64) {
        s_pk[i] = (int)(((uint32)relv << 25) | (uint32)NNZ_);   // dummy -> scratch y row
        s_src[i] = 0;
        s_val[i] = 0.f;
    }
}

// ------ LDS-token counting sort by relation + dst-rank; flattened coalesced copy-out ------
__global__ __launch_bounds__(256) void k_scatter(const int* __restrict__ rows, const int* __restrict__ cols,
                                                 const float* __restrict__ vals, int* __restrict__ rel_cur,
                                                 int* __restrict__ dst_cur,
                                                 int* __restrict__ s_pk, int* __restrict__ s_src,
                                                 float* __restrict__ s_val) {
    __shared__ int lcnt[RREL], lbase[RREL], gbase[RREL];
    __shared__ int stotal;
    __shared__ uint32 st[EPB];          // token: (rel<<12) | local_idx
    int t = threadIdx.x;
    size_t base = (size_t)blockIdx.x * EPB;
    if (t < RREL) lcnt[t] = 0;
    __syncthreads();
    int relv[16];
#pragma unroll
    for (int i = 0; i < 4; i++) {
        size_t k = base + (size_t)t * 16 + i * 4;
        int rr[4];
        if (k + 4 <= NNZ_) {
            int4 rw = *(const int4*)(rows + k);
            rr[0] = rw.x; rr[1] = rw.y; rr[2] = rw.z; rr[3] = rw.w;
        } else {
#pragma unroll
            for (int j = 0; j < 4; j++) rr[j] = (k + j < NNZ_) ? rows[k + j] : -1;
        }
#pragma unroll
        for (int j = 0; j < 4; j++) {
            if (rr[j] >= 0) {
                int rel = rr[j] / NNODES;
                relv[i * 4 + j] = rel;
                atomicAdd(&lcnt[rel], 1);
            } else relv[i * 4 + j] = -1;
        }
    }
    __syncthreads();
    if (t < 64) {                       // wave-0 scan of 51 bucket counts + global reserve
        int v = (t < RREL) ? lcnt[t] : 0;
        int sum = v;
#pragma unroll
        for (int off = 1; off < 64; off <<= 1) {
            int u = __shfl_up(sum, off, 64);
            if (t >= off) sum += u;
        }
        if (t < RREL) { lbase[t] = sum - v; gbase[t] = atomicAdd(&rel_cur[t], v); }
        if (t == RREL - 1) stotal = sum;
    }
    __syncthreads();
    if (t < RREL) lcnt[t] = 0;
    __syncthreads();
#pragma unroll
    for (int i = 0; i < 4; i++)
#pragma unroll
        for (int j = 0; j < 4; j++) {
            int rel = relv[i * 4 + j];
            if (rel >= 0) {
                int slot = lbase[rel] + atomicAdd(&lcnt[rel], 1);
                st[slot] = ((uint32)rel << 12) | (uint32)(t * 16 + i * 4 + j);
            }
        }
    __syncthreads();
    int total = stotal;                 // all 256 threads stream all buckets coalescedly
    for (int s2 = t; s2 < total; s2 += 256) {
        uint32 u = st[s2];
        int rel = (int)(u >> 12);
        size_t orig = base + (u & 4095u);
        int rw = rows[orig];            // L1/L2-hot re-reads within block window
        int dst = rw - rel * NNODES;
        int p = atomicAdd(&dst_cur[dst], 1);           // absolute dst-sorted slot
        int g = gbase[rel] + (s2 - lbase[rel]);
        s_pk[g] = (int)(((uint32)rel << 25) | (uint32)p);
        s_src[g] = cols[orig];
        s_val[g] = vals[orig];
    }
}

// ------- stage A (MFMA): y[p] = bf16( val * (Xb[src] @ W[rel]) ), C-layout stores -------
// FO=32: y row = 16 uints, uint i holds cols (i, i+16)  [interleaved pairs]
// FO=16: y row = 16 ushorts, sequential cols
template <int FO>
__global__ __launch_bounds__(256) void k_edgeA(const int* __restrict__ s_pk,
                                               const int* __restrict__ s_src,
                                               const float* __restrict__ s_val,
                                               const u32x4* __restrict__ Xb,
                                               const u32x4* __restrict__ Wb,
                                               uint32* __restrict__ y) {
    const int NT = FO / 16;          // N-tiles: 2 / 1
    const int NW = (FO == 32) ? 32 : 16;
    int t = threadIdx.x, lane = t & 63, wv = t >> 6;
    int ln15 = lane & 15, quad = lane >> 4;
    size_t k0 = (size_t)blockIdx.x * 512 + wv * 128;

    int pk0 = s_pk[k0 + lane],  pk1 = s_pk[k0 + 64 + lane];
    int sc0 = s_src[k0 + lane], sc1 = s_src[k0 + 64 + lane];
    float v0 = s_val[k0 + lane], v1 = s_val[k0 + 64 + lane];

    f32x4 acc[8][NT];
    const f32x4 zero = {0.f, 0.f, 0.f, 0.f};
#pragma unroll
    for (int s = 0; s < 8; s++) {
        int osc = (s < 4) ? sc0 : sc1;
        int opk = (s < 4) ? pk0 : pk1;
        int srcs = __shfl(osc, (s & 3) * 16 + ln15, 64);
        int rels = (int)(((uint32)__builtin_amdgcn_readfirstlane(__shfl(opk, (s & 3) * 16, 64))) >> 25);
        bf16x8 a = __builtin_bit_cast(bf16x8, Xb[(size_t)srcs * 4 + quad]);
#pragma unroll
        for (int tt = 0; tt < NT; tt++) {
            bf16x8 b = __builtin_bit_cast(bf16x8, Wb[(rels * 4 + quad) * NW + ln15 + 16 * tt]);
            acc[s][tt] = __builtin_amdgcn_mfma_f32_16x16x32_bf16(a, b, zero, 0, 0, 0);
        }
    }

    // epilogue in C-layout: edge e = (s&3)*16 + quad*4 + rg is spread over 16 lanes (ln15)
#pragma unroll
    for (int s = 0; s < 8; s++) {
        int opk = (s < 4) ? pk0 : pk1;
        float ov = (s < 4) ? v0 : v1;
#pragma unroll
        for (int rg = 0; rg < 4; rg++) {
            int e = (s & 3) * 16 + quad * 4 + rg;
            float ve = __shfl(ov, e, 64);
            int pe = __shfl(opk, e, 64) & 0x1FFFFFF;
            if (FO == 32) {
                uint32 val = pack_bf16x2(acc[s][0][rg] * ve, acc[s][1][rg] * ve);
                y[(size_t)pe * 16 + ln15] = val;               // 64 B/edge over 16 lanes
            } else {
                ((ushort*)y)[(size_t)pe * 16 + ln15] = bf16_1(acc[s][0][rg] * ve);
            }
        }
    }
}

// ------- stage B: segmented sum over dst-sorted y, fused bias(+relu) ------
template <int FO, bool RELU, bool BF16OUT>
__global__ __launch_bounds__(256) void k_segB(const uint32* __restrict__ y,
                                              const int* __restrict__ dst_base,
                                              const float* __restrict__ bias,
                                              void* __restrict__ outp) {
    const int UPR = FO / 2;        // uints per row
    const int QL = UPR / 4;        // u32x4 chunks per row: 4 / 2
    const int RPI = 64 / QL;       // rows per iteration: 16 / 32
    const bool ILV = (FO == 32);   // interleaved (c, c+16) pair layout
    int t = threadIdx.x, lane = t & 63, wv = t >> 6;
    int dst = blockIdx.x * 4 + wv;
    if (dst >= NNODES) return;
    int s = dst_base[dst], e2 = dst_base[dst + 1];
    int q = lane % QL, r = lane / QL;
    float acc[8];
#pragma unroll
    for (int j = 0; j < 8; j++) acc[j] = 0.f;
    for (int i = s + r; i < e2; i += RPI) {
        u32x4 u = __builtin_nontemporal_load((const u32x4*)(y + (size_t)i * UPR + 4 * q));
        acc[0] += unpack_lo(u.x); acc[1] += unpack_hi(u.x);
        acc[2] += unpack_lo(u.y); acc[3] += unpack_hi(u.y);
        acc[4] += unpack_lo(u.z); acc[5] += unpack_hi(u.z);
        acc[6] += unpack_lo(u.w); acc[7] += unpack_hi(u.w);
    }
#pragma unroll
    for (int off = 32; off >= QL; off >>= 1)
#pragma unroll
        for (int j = 0; j < 8; j++) acc[j] += __shfl_down(acc[j], off, 64);
    if (lane < QL) {
        float o[8];
        if (ILV) {
            // acc[2j] = col 4q+j ; acc[2j+1] = col 4q+16+j
#pragma unroll
            for (int j = 0; j < 4; j++) {
                o[2 * j]     = acc[2 * j]     + bias[4 * q + j];
                o[2 * j + 1] = acc[2 * j + 1] + bias[4 * q + 16 + j];
                if (RELU) { o[2 * j] = fmaxf(o[2 * j], 0.f); o[2 * j + 1] = fmaxf(o[2 * j + 1], 0.f); }
            }
        } else {
#pragma unroll
            for (int j = 0; j < 8; j++) {
                o[j] = acc[j] + bias[8 * q + j];
                if (RELU) o[j] = fmaxf(o[j], 0.f);
            }
        }
        if (BF16OUT) {
            if (ILV) {  // write sequential-pair bf16 rows (Xb layout for layer 2)
                u32x2 a0, a1;
                a0.x = pack_bf16x2(o[0], o[2]); a0.y = pack_bf16x2(o[4], o[6]);   // cols 4q..4q+3
                a1.x = pack_bf16x2(o[1], o[3]); a1.y = pack_bf16x2(o[5], o[7]);   // cols 4q+16..19
                ((u32x2*)outp)[(size_t)dst * 8 + q] = a0;
                ((u32x2*)outp)[(size_t)dst * 8 + 4 + q] = a1;
            } else {
                u32x4 pk;
                pk.x = pack_bf16x2(o[0], o[1]); pk.y = pack_bf16x2(o[2], o[3]);
                pk.z = pack_bf16x2(o[4], o[5]); pk.w = pack_bf16x2(o[6], o[7]);
                ((u32x4*)outp)[(size_t)dst * QL + q] = pk;
            }
        } else {
            float4* op = (float4*)outp;
            op[(size_t)dst * (FO / 4) + 2 * q]     = make_float4(o[0], o[1], o[2], o[3]);
            op[(size_t)dst * (FO / 4) + 2 * q + 1] = make_float4(o[4], o[5], o[6], o[7]);
        }
    }
}

extern "C" void kernel_launch(void* const* d_in, const int* in_sizes, int n_in,
                              void* d_out, int out_size, void* d_ws, size_t ws_size,
                              hipStream_t stream) {
    const float* features = (const float*)d_in[0];
    const float* vals     = (const float*)d_in[1];
    const float* comps1   = (const float*)d_in[2];
    const float* bases1   = (const float*)d_in[3];
    const float* bias1    = (const float*)d_in[4];
    const float* comps2   = (const float*)d_in[5];
    const float* bases2   = (const float*)d_in[6];
    const float* bias2    = (const float*)d_in[7];
    const int*   rows     = (const int*)d_in[8];
    const int*   cols     = (const int*)d_in[9];
    float* out = (float*)d_out;

    // ---- workspace layout (4-byte element offsets; all blocks 16 B-aligned) ----
    float* ws = (float*)d_ws;
    size_t o = 0;
    ushort* Wb1 = (ushort*)(ws + o); o += RREL * FIN * EDIM / 2;        // 26112
    ushort* Wb2 = (ushort*)(ws + o); o += RREL * EDIM * CDIM / 2;       // 13056
    o = (o + 3) & ~(size_t)3;
    uint32* Xb  = (uint32*)(ws + o); o += (size_t)NNODES * (FIN / 2);   // 0.8M
    uint32* h1b = (uint32*)(ws + o); o += (size_t)NNODES * (EDIM / 2);  // 0.8M
    int* s_pk  = (int*)(ws + o); o += CAP_;
    int* s_src = (int*)(ws + o); o += CAP_;
    float* s_val = ws + o;       o += CAP_;
    // contiguous zero region: rel_cnt, dst_cnt
    int* rel_cnt  = (int*)(ws + o); o += RREL + 1;
    int* dst_cnt  = (int*)(ws + o); o += NNODES;
    int* dst_cur  = (int*)(ws + o); o += NNODES;     // init by k_scan
    int* rel_cur  = (int*)(ws + o); o += RREL;
    int* pad_base = (int*)(ws + o); o += RREL + 1;
    o = (o + 3) & ~(size_t)3;
    int* dst_base = (int*)(ws + o); o += NNODES + 4;
    o = (o + 3) & ~(size_t)3;
    uint32* y = (uint32*)(ws + o);     // (NNZ_+1) rows x 16 uints, reused both layers

    const int NB = (NNZ_ + EPB - 1) / EPB;   // 489

    hipMemsetAsync(rel_cnt, 0, (RREL + 1 + NNODES) * sizeof(int), stream);

    k_weights<<<(RREL * FIN * EDIM + 255) / 256, 256, 0, stream>>>(comps1, bases1, comps2, bases2, Wb1, Wb2);
    k_tobf16<<<(NNODES * FIN / 2 + 255) / 256, 256, 0, stream>>>((const float2*)features, Xb, NNODES * FIN / 2);
    k_hist<<<NB, 256, 0, stream>>>(rows, rel_cnt, dst_cnt);
    k_scan<<<1, 1024, 0, stream>>>(dst_cnt, dst_base, dst_cur, rel_cnt, pad_base, rel_cur);
    k_padfill<<<RREL + 1, 64, 0, stream>>>(rel_cnt, pad_base, s_pk, s_src, s_val);
    k_scatter<<<NB, 256, 0, stream>>>(rows, cols, vals, rel_cur, dst_cur, s_pk, s_src, s_val);

    k_edgeA<EDIM><<<CAP_ / 512, 256, 0, stream>>>(s_pk, s_src, s_val, (const u32x4*)Xb,
                                                  (const u32x4*)Wb1, y);
    k_segB<EDIM, true, true><<<(NNODES + 3) / 4, 256, 0, stream>>>(y, dst_base, bias1, h1b);
    k_edgeA<CDIM><<<CAP_ / 512, 256, 0, stream>>>(s_pk, s_src, s_val, (const u32x4*)h1b,
                                                  (const u32x4*)Wb2, y);
    k_segB<CDIM, false, false><<<(NNODES + 3) / 4, 256, 0, stream>>>(y, dst_base, bias2, out);
}

// Round 7
// 459.423 us; speedup vs baseline: 2.0271x; 1.0089x over previous
//
#include <hip/hip_runtime.h>

#define NNODES 50000
#define RREL 51
#define FIN 32
#define EDIM 32
#define CDIM 16
#define BB 30
#define NNZ_ 2000000
#define CAP_ 2000896   // ceil((NNZ_ + 51*15)/512)*512 : padded edge capacity
#define EPB 4096       // edges per block in hist/scatter

typedef unsigned int uint32;
typedef unsigned short ushort;
typedef uint32 u32x2 __attribute__((ext_vector_type(2)));
typedef uint32 u32x4 __attribute__((ext_vector_type(4)));
typedef short bf16x8 __attribute__((ext_vector_type(8)));
typedef float f32x4 __attribute__((ext_vector_type(4)));

// ---------- bf16 helpers (manual RNE) ----------
static __device__ __forceinline__ uint32 pack_bf16x2(float a, float b) {
    uint32 ua = __builtin_bit_cast(uint32, a);
    uint32 ub = __builtin_bit_cast(uint32, b);
    ua += 0x7fffu + ((ua >> 16) & 1u);
    ub += 0x7fffu + ((ub >> 16) & 1u);
    return (ua >> 16) | (ub & 0xffff0000u);
}
static __device__ __forceinline__ ushort bf16_1(float x) {
    uint32 u = __builtin_bit_cast(uint32, x);
    u += 0x7fffu + ((u >> 16) & 1u);
    return (ushort)(u >> 16);
}
static __device__ __forceinline__ float unpack_lo(uint32 u) { return __builtin_bit_cast(float, u << 16); }
static __device__ __forceinline__ float unpack_hi(uint32 u) { return __builtin_bit_cast(float, u & 0xffff0000u); }

// ---- weight build into MFMA-B-swizzled bf16 layout: Wb[r][kchunk][n][j], k=8*kchunk+j ----
__global__ void k_weights(const float* __restrict__ comps1, const float* __restrict__ bases1,
                          const float* __restrict__ comps2, const float* __restrict__ bases2,
                          ushort* __restrict__ Wb1, ushort* __restrict__ Wb2) {
    int i = blockIdx.x * 256 + threadIdx.x;
    if (i < RREL * FIN * EDIM) {          // (r, f, e): f = k index, e = n index
        int r = i >> 10, fe = i & 1023, f = fe >> 5, e = fe & 31;
        float acc = 0.f;
#pragma unroll
        for (int b = 0; b < BB; b++) acc += comps1[r * BB + b] * bases1[b * 1024 + fe];
        Wb1[((r * 4 + (f >> 3)) * 32 + e) * 8 + (f & 7)] = bf16_1(acc);
    }
    if (i < RREL * EDIM * CDIM) {         // (r, k, c)
        int r = i >> 9, ec = i & 511, kk = ec >> 4, c = ec & 15;
        float acc = 0.f;
#pragma unroll
        for (int b = 0; b < BB; b++) acc += comps2[r * BB + b] * bases2[b * 512 + ec];
        Wb2[((r * 4 + (kk >> 3)) * 16 + c) * 8 + (kk & 7)] = bf16_1(acc);
    }
}

// ---------------- fp32 features -> packed bf16 rows (64 B/row, L2-resident) ----------
__global__ void k_tobf16(const float2* __restrict__ src, uint32* __restrict__ dst, int n2) {
    int i = blockIdx.x * 256 + threadIdx.x;
    if (i < n2) {
        float2 f = src[i];
        dst[i] = pack_bf16x2(f.x, f.y);
    }
}

// ------------- histograms: 1024 thr/block, 4 edges/thread (int4) -------------
__global__ __launch_bounds__(1024) void k_hist(const int* __restrict__ rows,
                                               int* __restrict__ rel_cnt,
                                               int* __restrict__ dst_cnt) {
    __shared__ int lc[RREL];
    int t = threadIdx.x;
    if (t < RREL) lc[t] = 0;
    __syncthreads();
    size_t k = (size_t)blockIdx.x * EPB + (size_t)t * 4;
    int rr[4];
    if (k + 4 <= NNZ_) {
        int4 rw = *(const int4*)(rows + k);
        rr[0] = rw.x; rr[1] = rw.y; rr[2] = rw.z; rr[3] = rw.w;
    } else {
#pragma unroll
        for (int j = 0; j < 4; j++) rr[j] = (k + j < NNZ_) ? rows[k + j] : -1;
    }
#pragma unroll
    for (int j = 0; j < 4; j++) {
        if (rr[j] >= 0) {
            int rel = rr[j] / NNODES;
            atomicAdd(&lc[rel], 1);
            atomicAdd(&dst_cnt[rr[j] - rel * NNODES], 1);
        }
    }
    __syncthreads();
    if (t < RREL) atomicAdd(&rel_cnt[t], lc[t]);
}

// ---- single-block scan: dst_cnt -> dst_base AND dst_cur (cursor starts at base);
// ---- fused 16-aligned rel prefix ----
__global__ __launch_bounds__(1024) void k_scan(const int* __restrict__ cnt, int* __restrict__ base,
                                               int* __restrict__ cur,
                                               const int* __restrict__ rel_cnt,
                                               int* __restrict__ pad_base, int* __restrict__ rel_cur) {
    __shared__ int ssum[1024];
    int t = threadIdx.x;
    const int CH = 52;                 // 13 int4s per thread; 1024*52 >= NNODES
    int lo = t * CH;
    int s = 0;
#pragma unroll
    for (int c = 0; c < 13; c++) {
        int i = lo + c * 4;
        if (i + 4 <= NNODES) {
            int4 q = *(const int4*)(cnt + i);
            s += q.x + q.y + q.z + q.w;
        } else {
            for (int j = 0; j < 4; j++) if (i + j < NNODES) s += cnt[i + j];
        }
    }
    ssum[t] = s;
    if (t == 0) {                      // fused rel prefix (others proceed to barrier)
        int a = 0;
        for (int r = 0; r < RREL; r++) {
            pad_base[r] = a; rel_cur[r] = a;
            a += (rel_cnt[r] + 15) & ~15;
        }
        pad_base[RREL] = a;
    }
    __syncthreads();
    for (int off = 1; off < 1024; off <<= 1) {
        int u = (t >= off) ? ssum[t - off] : 0;
        __syncthreads();
        ssum[t] += u;
        __syncthreads();
    }
    int run = (t == 0) ? 0 : ssum[t - 1];
#pragma unroll
    for (int c = 0; c < 13; c++) {
        int i = lo + c * 4;
        if (i + 4 <= NNODES) {
            int4 q = *(const int4*)(cnt + i);
            int4 w;
            w.x = run; run += q.x; w.y = run; run += q.y;
            w.z = run; run += q.z; w.w = run; run += q.w;
            *(int4*)(base + i) = w;
            *(int4*)(cur + i) = w;
        } else {
            for (int j = 0; j < 4; j++) if (i + j < NNODES) {
                base[i + j] = run; cur[i + j] = run; run += cnt[i + j];
            }
        }
    }
    if (t == 1023) base[NNODES] = run;
}

// fill padding gaps with dummy edges (rel = segment rel so subtiles stay rel-uniform)
__global__ void k_padfill(const int* __restrict__ rel_cnt, const int* __restrict__ pad_base,
                          int* __restrict__ s_pk, int* __restrict__ s_src,
                          float* __restrict__ s_val) {
    int r = blockIdx.x;
    int start, end, relv;
    if (r < RREL) { start = pad_base[r] + rel_cnt[r]; end = pad_base[r + 1]; relv = r; }
    else { start = pad_base[RREL]; end = CAP_; relv = 0; }
    for (int i = start + threadIdx.x; i < end; i += 64) {
        s_pk[i] = (int)(((uint32)relv << 25) | (uint32)NNZ_);   // dummy -> scratch y row
        s_src[i] = 0;
        s_val[i] = 0.f;
    }
}

// ------ LDS-token counting sort by relation + dst-rank; 1024 thr, dst-first tokens ------
__global__ __launch_bounds__(1024) void k_scatter(const int* __restrict__ rows, const int* __restrict__ cols,
                                                  const float* __restrict__ vals, int* __restrict__ rel_cur,
                                                  int* __restrict__ dst_cur,
                                                  int* __restrict__ s_pk, int* __restrict__ s_src,
                                                  float* __restrict__ s_val) {
    __shared__ int lcnt[RREL], lbase[RREL], gbase[RREL];
    __shared__ int stotal;
    __shared__ uint32 st[EPB];          // token: (dst<<12) | local_idx
    int t = threadIdx.x;
    size_t base = (size_t)blockIdx.x * EPB;
    if (t < RREL) lcnt[t] = 0;
    __syncthreads();
    size_t k = base + (size_t)t * 4;
    int relv[4], dstv[4];
    {
        int rr[4];
        if (k + 4 <= NNZ_) {
            int4 rw = *(const int4*)(rows + k);
            rr[0] = rw.x; rr[1] = rw.y; rr[2] = rw.z; rr[3] = rw.w;
        } else {
#pragma unroll
            for (int j = 0; j < 4; j++) rr[j] = (k + j < NNZ_) ? rows[k + j] : -1;
        }
#pragma unroll
        for (int j = 0; j < 4; j++) {
            if (rr[j] >= 0) {
                int rel = rr[j] / NNODES;
                relv[j] = rel;
                dstv[j] = rr[j] - rel * NNODES;
                atomicAdd(&lcnt[rel], 1);
            } else relv[j] = -1;
        }
    }
    __syncthreads();
    if (t < 64) {                       // wave-0 scan of 51 bucket counts + global reserve
        int v = (t < RREL) ? lcnt[t] : 0;
        int sum = v;
#pragma unroll
        for (int off = 1; off < 64; off <<= 1) {
            int u = __shfl_up(sum, off, 64);
            if (t >= off) sum += u;
        }
        if (t < RREL) { lbase[t] = sum - v; gbase[t] = atomicAdd(&rel_cur[t], v); }
        if (t == RREL - 1) stotal = sum;
    }
    __syncthreads();
    if (t < RREL) lcnt[t] = 0;
    __syncthreads();
#pragma unroll
    for (int j = 0; j < 4; j++) {
        int rel = relv[j];
        if (rel >= 0) {
            int slot = lbase[rel] + atomicAdd(&lcnt[rel], 1);
            st[slot] = ((uint32)dstv[j] << 12) | (uint32)(t * 4 + j);
        }
    }
    __syncthreads();
    int total = stotal;
    // 4 independent iterations: dst-rank atomic launches straight off the LDS token,
    // rows/cols/vals reloads (L1/L2-hot) proceed in parallel off the critical path.
#pragma unroll
    for (int i = 0; i < 4; i++) {
        int s2 = t + i * 1024;
        if (s2 < total) {
            uint32 u = st[s2];
            int dst = (int)(u >> 12);
            int p = atomicAdd(&dst_cur[dst], 1);       // absolute dst-sorted slot
            size_t orig = base + (u & 4095u);
            int rel = rows[orig] / NNODES;
            int g = gbase[rel] + (s2 - lbase[rel]);
            s_pk[g] = (int)(((uint32)rel << 25) | (uint32)p);
            s_src[g] = cols[orig];
            s_val[g] = vals[orig];
        }
    }
}

// ------- stage A (MFMA): y[p] = bf16( val * (Xb[src] @ W[rel]) ), C-layout stores -------
// FO=32: y row = 16 uints, uint i holds cols (i, i+16)  [interleaved pairs]
// FO=16: y row = 16 ushorts, sequential cols
template <int FO>
__global__ __launch_bounds__(256) void k_edgeA(const int* __restrict__ s_pk,
                                               const int* __restrict__ s_src,
                                               const float* __restrict__ s_val,
                                               const u32x4* __restrict__ Xb,
                                               const u32x4* __restrict__ Wb,
                                               uint32* __restrict__ y) {
    const int NT = FO / 16;          // N-tiles: 2 / 1
    const int NW = (FO == 32) ? 32 : 16;
    int t = threadIdx.x, lane = t & 63, wv = t >> 6;
    int ln15 = lane & 15, quad = lane >> 4;
    size_t k0 = (size_t)blockIdx.x * 512 + wv * 128;

    int pk0 = s_pk[k0 + lane],  pk1 = s_pk[k0 + 64 + lane];
    int sc0 = s_src[k0 + lane], sc1 = s_src[k0 + 64 + lane];
    float v0 = s_val[k0 + lane], v1 = s_val[k0 + 64 + lane];

    f32x4 acc[8][NT];
    const f32x4 zero = {0.f, 0.f, 0.f, 0.f};
#pragma unroll
    for (int s = 0; s < 8; s++) {
        int osc = (s < 4) ? sc0 : sc1;
        int opk = (s < 4) ? pk0 : pk1;
        int srcs = __shfl(osc, (s & 3) * 16 + ln15, 64);
        int rels = (int)(((uint32)__builtin_amdgcn_readfirstlane(__shfl(opk, (s & 3) * 16, 64))) >> 25);
        bf16x8 a = __builtin_bit_cast(bf16x8, Xb[(size_t)srcs * 4 + quad]);
#pragma unroll
        for (int tt = 0; tt < NT; tt++) {
            bf16x8 b = __builtin_bit_cast(bf16x8, Wb[(rels * 4 + quad) * NW + ln15 + 16 * tt]);
            acc[s][tt] = __builtin_amdgcn_mfma_f32_16x16x32_bf16(a, b, zero, 0, 0, 0);
        }
    }

    // epilogue in C-layout: edge e = (s&3)*16 + quad*4 + rg is spread over 16 lanes (ln15)
#pragma unroll
    for (int s = 0; s < 8; s++) {
        int opk = (s < 4) ? pk0 : pk1;
        float ov = (s < 4) ? v0 : v1;
#pragma unroll
        for (int rg = 0; rg < 4; rg++) {
            int e = (s & 3) * 16 + quad * 4 + rg;
            float ve = __shfl(ov, e, 64);
            int pe = __shfl(opk, e, 64) & 0x1FFFFFF;
            if (FO == 32) {
                uint32 val = pack_bf16x2(acc[s][0][rg] * ve, acc[s][1][rg] * ve);
                y[(size_t)pe * 16 + ln15] = val;               // 64 B/edge over 16 lanes
            } else {
                ((ushort*)y)[(size_t)pe * 16 + ln15] = bf16_1(acc[s][0][rg] * ve);
            }
        }
    }
}

// ------- stage B: segmented sum over dst-sorted y, fused bias(+relu) ------
template <int FO, bool RELU, bool BF16OUT>
__global__ __launch_bounds__(256) void k_segB(const uint32* __restrict__ y,
                                              const int* __restrict__ dst_base,
                                              const float* __restrict__ bias,
                                              void* __restrict__ outp) {
    const int UPR = FO / 2;        // uints per row
    const int QL = UPR / 4;        // u32x4 chunks per row: 4 / 2
    const int RPI = 64 / QL;       // rows per iteration: 16 / 32
    const bool ILV = (FO == 32);   // interleaved (c, c+16) pair layout
    int t = threadIdx.x, lane = t & 63, wv = t >> 6;
    int dst = blockIdx.x * 4 + wv;
    if (dst >= NNODES) return;
    int s = dst_base[dst], e2 = dst_base[dst + 1];
    int q = lane % QL, r = lane / QL;
    float acc[8];
#pragma unroll
    for (int j = 0; j < 8; j++) acc[j] = 0.f;
    for (int i = s + r; i < e2; i += RPI) {
        u32x4 u = __builtin_nontemporal_load((const u32x4*)(y + (size_t)i * UPR + 4 * q));
        acc[0] += unpack_lo(u.x); acc[1] += unpack_hi(u.x);
        acc[2] += unpack_lo(u.y); acc[3] += unpack_hi(u.y);
        acc[4] += unpack_lo(u.z); acc[5] += unpack_hi(u.z);
        acc[6] += unpack_lo(u.w); acc[7] += unpack_hi(u.w);
    }
#pragma unroll
    for (int off = 32; off >= QL; off >>= 1)
#pragma unroll
        for (int j = 0; j < 8; j++) acc[j] += __shfl_down(acc[j], off, 64);
    if (lane < QL) {
        float o[8];
        if (ILV) {
            // acc[2j] = col 4q+j ; acc[2j+1] = col 4q+16+j
#pragma unroll
            for (int j = 0; j < 4; j++) {
                o[2 * j]     = acc[2 * j]     + bias[4 * q + j];
                o[2 * j + 1] = acc[2 * j + 1] + bias[4 * q + 16 + j];
                if (RELU) { o[2 * j] = fmaxf(o[2 * j], 0.f); o[2 * j + 1] = fmaxf(o[2 * j + 1], 0.f); }
            }
        } else {
#pragma unroll
            for (int j = 0; j < 8; j++) {
                o[j] = acc[j] + bias[8 * q + j];
                if (RELU) o[j] = fmaxf(o[j], 0.f);
            }
        }
        if (BF16OUT) {
            if (ILV) {  // write sequential-pair bf16 rows (Xb layout for layer 2)
                u32x2 a0, a1;
                a0.x = pack_bf16x2(o[0], o[2]); a0.y = pack_bf16x2(o[4], o[6]);   // cols 4q..4q+3
                a1.x = pack_bf16x2(o[1], o[3]); a1.y = pack_bf16x2(o[5], o[7]);   // cols 4q+16..19
                ((u32x2*)outp)[(size_t)dst * 8 + q] = a0;
                ((u32x2*)outp)[(size_t)dst * 8 + 4 + q] = a1;
            } else {
                u32x4 pk;
                pk.x = pack_bf16x2(o[0], o[1]); pk.y = pack_bf16x2(o[2], o[3]);
                pk.z = pack_bf16x2(o[4], o[5]); pk.w = pack_bf16x2(o[6], o[7]);
                ((u32x4*)outp)[(size_t)dst * QL + q] = pk;
            }
        } else {
            float4* op = (float4*)outp;
            op[(size_t)dst * (FO / 4) + 2 * q]     = make_float4(o[0], o[1], o[2], o[3]);
            op[(size_t)dst * (FO / 4) + 2 * q + 1] = make_float4(o[4], o[5], o[6], o[7]);
        }
    }
}

extern "C" void kernel_launch(void* const* d_in, const int* in_sizes, int n_in,
                              void* d_out, int out_size, void* d_ws, size_t ws_size,
                              hipStream_t stream) {
    const float* features = (const float*)d_in[0];
    const float* vals     = (const float*)d_in[1];
    const float* comps1   = (const float*)d_in[2];
    const float* bases1   = (const float*)d_in[3];
    const float* bias1    = (const float*)d_in[4];
    const float* comps2   = (const float*)d_in[5];
    const float* bases2   = (const float*)d_in[6];
    const float* bias2    = (const float*)d_in[7];
    const int*   rows     = (const int*)d_in[8];
    const int*   cols     = (const int*)d_in[9];
    float* out = (float*)d_out;

    // ---- workspace layout (4-byte element offsets; all blocks 16 B-aligned) ----
    float* ws = (float*)d_ws;
    size_t o = 0;
    ushort* Wb1 = (ushort*)(ws + o); o += RREL * FIN * EDIM / 2;        // 26112
    ushort* Wb2 = (ushort*)(ws + o); o += RREL * EDIM * CDIM / 2;       // 13056
    o = (o + 3) & ~(size_t)3;
    uint32* Xb  = (uint32*)(ws + o); o += (size_t)NNODES * (FIN / 2);   // 0.8M
    uint32* h1b = (uint32*)(ws + o); o += (size_t)NNODES * (EDIM / 2);  // 0.8M
    int* s_pk  = (int*)(ws + o); o += CAP_;
    int* s_src = (int*)(ws + o); o += CAP_;
    float* s_val = ws + o;       o += CAP_;
    // contiguous zero region: rel_cnt, dst_cnt
    int* rel_cnt  = (int*)(ws + o); o += RREL + 1;
    int* dst_cnt  = (int*)(ws + o); o += NNODES;
    int* dst_cur  = (int*)(ws + o); o += NNODES;     // init by k_scan
    int* rel_cur  = (int*)(ws + o); o += RREL;
    int* pad_base = (int*)(ws + o); o += RREL + 1;
    o = (o + 3) & ~(size_t)3;
    int* dst_base = (int*)(ws + o); o += NNODES + 4;
    o = (o + 3) & ~(size_t)3;
    uint32* y = (uint32*)(ws + o);     // (NNZ_+1) rows x 16 uints, reused both layers

    const int NB = (NNZ_ + EPB - 1) / EPB;   // 489

    hipMemsetAsync(rel_cnt, 0, (RREL + 1 + NNODES) * sizeof(int), stream);

    k_weights<<<(RREL * FIN * EDIM + 255) / 256, 256, 0, stream>>>(comps1, bases1, comps2, bases2, Wb1, Wb2);
    k_tobf16<<<(NNODES * FIN / 2 + 255) / 256, 256, 0, stream>>>((const float2*)features, Xb, NNODES * FIN / 2);
    k_hist<<<NB, 1024, 0, stream>>>(rows, rel_cnt, dst_cnt);
    k_scan<<<1, 1024, 0, stream>>>(dst_cnt, dst_base, dst_cur, rel_cnt, pad_base, rel_cur);
    k_padfill<<<RREL + 1, 64, 0, stream>>>(rel_cnt, pad_base, s_pk, s_src, s_val);
    k_scatter<<<NB, 1024, 0, stream>>>(rows, cols, vals, rel_cur, dst_cur, s_pk, s_src, s_val);

    k_edgeA<EDIM><<<CAP_ / 512, 256, 0, stream>>>(s_pk, s_src, s_val, (const u32x4*)Xb,
                                                  (const u32x4*)Wb1, y);
    k_segB<EDIM, true, true><<<(NNODES + 3) / 4, 256, 0, stream>>>(y, dst_base, bias1, h1b);
    k_edgeA<CDIM><<<CAP_ / 512, 256, 0, stream>>>(s_pk, s_src, s_val, (const u32x4*)h1b,
                                                  (const u32x4*)Wb2, y);
    k_segB<CDIM, false, false><<<(NNODES + 3) / 4, 256, 0, stream>>>(y, dst_base, bias2, out);
}

// Round 8
// 392.349 us; speedup vs baseline: 2.3736x; 1.1710x over previous
//
#include <hip/hip_runtime.h>

#define NNODES 50000
#define RREL 51
#define FIN 32
#define EDIM 32
#define CDIM 16
#define BB 30
#define NNZ_ 2000000
#define CAP_ 2000896   // ceil((NNZ_ + 51*15)/512)*512 : padded edge capacity
#define EPB 4096       // edges per block in hist/scatter
#define MAXDEG 128     // virtual per-dst rank stride (max true degree ~78)

typedef unsigned int uint32;
typedef unsigned short ushort;
typedef uint32 u32x2 __attribute__((ext_vector_type(2)));
typedef uint32 u32x4 __attribute__((ext_vector_type(4)));
typedef short bf16x8 __attribute__((ext_vector_type(8)));
typedef float f32x4 __attribute__((ext_vector_type(4)));

// ---------- bf16 helpers (manual RNE) ----------
static __device__ __forceinline__ uint32 pack_bf16x2(float a, float b) {
    uint32 ua = __builtin_bit_cast(uint32, a);
    uint32 ub = __builtin_bit_cast(uint32, b);
    ua += 0x7fffu + ((ua >> 16) & 1u);
    ub += 0x7fffu + ((ub >> 16) & 1u);
    return (ua >> 16) | (ub & 0xffff0000u);
}
static __device__ __forceinline__ ushort bf16_1(float x) {
    uint32 u = __builtin_bit_cast(uint32, x);
    u += 0x7fffu + ((u >> 16) & 1u);
    return (ushort)(u >> 16);
}
static __device__ __forceinline__ float unpack_lo(uint32 u) { return __builtin_bit_cast(float, u << 16); }
static __device__ __forceinline__ float unpack_hi(uint32 u) { return __builtin_bit_cast(float, u & 0xffff0000u); }

// ---- weight build into MFMA-B-swizzled bf16 layout: Wb[r][kchunk][n][j], k=8*kchunk+j ----
__global__ void k_weights(const float* __restrict__ comps1, const float* __restrict__ bases1,
                          const float* __restrict__ comps2, const float* __restrict__ bases2,
                          ushort* __restrict__ Wb1, ushort* __restrict__ Wb2) {
    int i = blockIdx.x * 256 + threadIdx.x;
    if (i < RREL * FIN * EDIM) {          // (r, f, e): f = k index, e = n index
        int r = i >> 10, fe = i & 1023, f = fe >> 5, e = fe & 31;
        float acc = 0.f;
#pragma unroll
        for (int b = 0; b < BB; b++) acc += comps1[r * BB + b] * bases1[b * 1024 + fe];
        Wb1[((r * 4 + (f >> 3)) * 32 + e) * 8 + (f & 7)] = bf16_1(acc);
    }
    if (i < RREL * EDIM * CDIM) {         // (r, k, c)
        int r = i >> 9, ec = i & 511, kk = ec >> 4, c = ec & 15;
        float acc = 0.f;
#pragma unroll
        for (int b = 0; b < BB; b++) acc += comps2[r * BB + b] * bases2[b * 512 + ec];
        Wb2[((r * 4 + (kk >> 3)) * 16 + c) * 8 + (kk & 7)] = bf16_1(acc);
    }
}

// ---------------- fp32 features -> packed bf16 rows (64 B/row, L2-resident) ----------
__global__ void k_tobf16(const float2* __restrict__ src, uint32* __restrict__ dst, int n2) {
    int i = blockIdx.x * 256 + threadIdx.x;
    if (i < n2) {
        float2 f = src[i];
        dst[i] = pack_bf16x2(f.x, f.y);
    }
}

// ------------- relation histogram only: LDS atomics, streaming read -------------
__global__ __launch_bounds__(1024) void k_relhist(const int* __restrict__ rows,
                                                  int* __restrict__ rel_cnt) {
    __shared__ int lc[RREL];
    int t = threadIdx.x;
    if (t < RREL) lc[t] = 0;
    __syncthreads();
    size_t k = (size_t)blockIdx.x * EPB + (size_t)t * 4;
    int rr[4];
    if (k + 4 <= NNZ_) {
        int4 rw = *(const int4*)(rows + k);
        rr[0] = rw.x; rr[1] = rw.y; rr[2] = rw.z; rr[3] = rw.w;
    } else {
#pragma unroll
        for (int j = 0; j < 4; j++) rr[j] = (k + j < NNZ_) ? rows[k + j] : -1;
    }
#pragma unroll
    for (int j = 0; j < 4; j++)
        if (rr[j] >= 0) atomicAdd(&lc[rr[j] / NNODES], 1);
    __syncthreads();
    if (t < RREL) atomicAdd(&rel_cnt[t], lc[t]);
}

// ---- tiny 16-aligned rel prefix ----
__global__ void k_relscan(const int* __restrict__ rel_cnt, int* __restrict__ pad_base,
                          int* __restrict__ rel_cur) {
    if (threadIdx.x == 0) {
        int a = 0;
        for (int r = 0; r < RREL; r++) {
            pad_base[r] = a; rel_cur[r] = a;
            a += (rel_cnt[r] + 15) & ~15;
        }
        pad_base[RREL] = a;
    }
}

// fill padding gaps with dummy edges (rel = segment rel so subtiles stay rel-uniform)
__global__ void k_padfill(const int* __restrict__ rel_cnt, const int* __restrict__ pad_base,
                          int* __restrict__ s_pk, int* __restrict__ s_src,
                          float* __restrict__ s_val) {
    int r = blockIdx.x;
    int start, end, relv;
    if (r < RREL) { start = pad_base[r] + rel_cnt[r]; end = pad_base[r + 1]; relv = r; }
    else { start = pad_base[RREL]; end = CAP_; relv = 0; }
    uint32 pdum = (uint32)NNODES * MAXDEG;   // virtual p -> maps to scratch row after translate
    for (int i = start + threadIdx.x; i < end; i += 64) {
        s_pk[i] = (int)(((uint32)relv << 25) | pdum);
        s_src[i] = 0;
        s_val[i] = 0.f;
    }
}

// ------ LDS-token counting sort by relation + VIRTUAL dst-rank (zero-based atomic) ------
__global__ __launch_bounds__(1024) void k_scatter(const int* __restrict__ rows, const int* __restrict__ cols,
                                                  const float* __restrict__ vals, int* __restrict__ rel_cur,
                                                  int* __restrict__ dst_rank,
                                                  int* __restrict__ s_pk, int* __restrict__ s_src,
                                                  float* __restrict__ s_val) {
    __shared__ int lcnt[RREL], lbase[RREL], gbase[RREL];
    __shared__ int stotal;
    __shared__ uint32 st[EPB];          // token: (dst<<12) | local_idx
    int t = threadIdx.x;
    size_t base = (size_t)blockIdx.x * EPB;
    if (t < RREL) lcnt[t] = 0;
    __syncthreads();
    size_t k = base + (size_t)t * 4;
    int relv[4], dstv[4];
    {
        int rr[4];
        if (k + 4 <= NNZ_) {
            int4 rw = *(const int4*)(rows + k);
            rr[0] = rw.x; rr[1] = rw.y; rr[2] = rw.z; rr[3] = rw.w;
        } else {
#pragma unroll
            for (int j = 0; j < 4; j++) rr[j] = (k + j < NNZ_) ? rows[k + j] : -1;
        }
#pragma unroll
        for (int j = 0; j < 4; j++) {
            if (rr[j] >= 0) {
                int rel = rr[j] / NNODES;
                relv[j] = rel;
                dstv[j] = rr[j] - rel * NNODES;
                atomicAdd(&lcnt[rel], 1);
            } else relv[j] = -1;
        }
    }
    __syncthreads();
    if (t < 64) {                       // wave-0 scan of 51 bucket counts + global reserve
        int v = (t < RREL) ? lcnt[t] : 0;
        int sum = v;
#pragma unroll
        for (int off = 1; off < 64; off <<= 1) {
            int u = __shfl_up(sum, off, 64);
            if (t >= off) sum += u;
        }
        if (t < RREL) { lbase[t] = sum - v; gbase[t] = atomicAdd(&rel_cur[t], v); }
        if (t == RREL - 1) stotal = sum;
    }
    __syncthreads();
    if (t < RREL) lcnt[t] = 0;
    __syncthreads();
#pragma unroll
    for (int j = 0; j < 4; j++) {
        int rel = relv[j];
        if (rel >= 0) {
            int slot = lbase[rel] + atomicAdd(&lcnt[rel], 1);
            st[slot] = ((uint32)dstv[j] << 12) | (uint32)(t * 4 + j);
        }
    }
    __syncthreads();
    int total = stotal;
#pragma unroll
    for (int i = 0; i < 4; i++) {
        int s2 = t + i * 1024;
        if (s2 < total) {
            uint32 u = st[s2];
            int dst = (int)(u >> 12);
            int p = dst * MAXDEG + atomicAdd(&dst_rank[dst], 1);   // virtual slot
            size_t orig = base + (u & 4095u);
            int rel = rows[orig] / NNODES;
            int g = gbase[rel] + (s2 - lbase[rel]);
            s_pk[g] = (int)(((uint32)rel << 25) | (uint32)p);
            s_src[g] = cols[orig];
            s_val[g] = vals[orig];
        }
    }
}

// ---- single-block scan: dst_rank -> dst_base[0..N] (int4) ----
__global__ __launch_bounds__(1024) void k_scan(const int* __restrict__ cnt, int* __restrict__ base) {
    __shared__ int ssum[1024];
    int t = threadIdx.x;
    const int CH = 52;                 // 13 int4s per thread; 1024*52 >= NNODES
    int lo = t * CH;
    int s = 0;
#pragma unroll
    for (int c = 0; c < 13; c++) {
        int i = lo + c * 4;
        if (i + 4 <= NNODES) {
            int4 q = *(const int4*)(cnt + i);
            s += q.x + q.y + q.z + q.w;
        } else {
            for (int j = 0; j < 4; j++) if (i + j < NNODES) s += cnt[i + j];
        }
    }
    ssum[t] = s;
    __syncthreads();
    for (int off = 1; off < 1024; off <<= 1) {
        int u = (t >= off) ? ssum[t - off] : 0;
        __syncthreads();
        ssum[t] += u;
        __syncthreads();
    }
    int run = (t == 0) ? 0 : ssum[t - 1];
#pragma unroll
    for (int c = 0; c < 13; c++) {
        int i = lo + c * 4;
        if (i + 4 <= NNODES) {
            int4 q = *(const int4*)(cnt + i);
            int4 w;
            w.x = run; run += q.x; w.y = run; run += q.y;
            w.z = run; run += q.z; w.w = run; run += q.w;
            *(int4*)(base + i) = w;
        } else {
            for (int j = 0; j < 4; j++) if (i + j < NNODES) { base[i + j] = run; run += cnt[i + j]; }
        }
    }
    if (t == 1023) base[NNODES] = run;   // == total (tail threads have empty chunks)
}

// ---- translate virtual p -> compact dst-sorted slot: p' = dst_base[p/128] + p%128 ----
__global__ __launch_bounds__(256) void k_translate(int* __restrict__ s_pk,
                                                   const int* __restrict__ dst_base) {
    int i = blockIdx.x * 256 + threadIdx.x;     // CAP_/4 int4s, grid sized exactly
    int4 v = ((const int4*)s_pk)[i];
    int* c = &v.x;
#pragma unroll
    for (int j = 0; j < 4; j++) {
        uint32 pk = (uint32)c[j];
        uint32 p = pk & 0x1FFFFFFu;
        int dst = (int)(p >> 7);                // MAXDEG = 128
        int compact = dst_base[dst] + (int)(p & 127u);
        c[j] = (int)((pk & 0xFE000000u) | (uint32)compact);
    }
    ((int4*)s_pk)[i] = v;
}

// ------- stage A (MFMA): y[p] = bf16( val * (Xb[src] @ W[rel]) ), C-layout stores -------
// FO=32: y row = 16 uints, uint i holds cols (i, i+16)  [interleaved pairs]
// FO=16: y row = 16 ushorts, sequential cols
template <int FO>
__global__ __launch_bounds__(256) void k_edgeA(const int* __restrict__ s_pk,
                                               const int* __restrict__ s_src,
                                               const float* __restrict__ s_val,
                                               const u32x4* __restrict__ Xb,
                                               const u32x4* __restrict__ Wb,
                                               uint32* __restrict__ y) {
    const int NT = FO / 16;          // N-tiles: 2 / 1
    const int NW = (FO == 32) ? 32 : 16;
    int t = threadIdx.x, lane = t & 63, wv = t >> 6;
    int ln15 = lane & 15, quad = lane >> 4;
    size_t k0 = (size_t)blockIdx.x * 512 + wv * 128;

    int pk0 = s_pk[k0 + lane],  pk1 = s_pk[k0 + 64 + lane];
    int sc0 = s_src[k0 + lane], sc1 = s_src[k0 + 64 + lane];
    float v0 = s_val[k0 + lane], v1 = s_val[k0 + 64 + lane];

    f32x4 acc[8][NT];
    const f32x4 zero = {0.f, 0.f, 0.f, 0.f};
#pragma unroll
    for (int s = 0; s < 8; s++) {
        int osc = (s < 4) ? sc0 : sc1;
        int opk = (s < 4) ? pk0 : pk1;
        int srcs = __shfl(osc, (s & 3) * 16 + ln15, 64);
        int rels = (int)(((uint32)__builtin_amdgcn_readfirstlane(__shfl(opk, (s & 3) * 16, 64))) >> 25);
        bf16x8 a = __builtin_bit_cast(bf16x8, Xb[(size_t)srcs * 4 + quad]);
#pragma unroll
        for (int tt = 0; tt < NT; tt++) {
            bf16x8 b = __builtin_bit_cast(bf16x8, Wb[(rels * 4 + quad) * NW + ln15 + 16 * tt]);
            acc[s][tt] = __builtin_amdgcn_mfma_f32_16x16x32_bf16(a, b, zero, 0, 0, 0);
        }
    }

    // epilogue in C-layout: edge e = (s&3)*16 + quad*4 + rg is spread over 16 lanes (ln15)
#pragma unroll
    for (int s = 0; s < 8; s++) {
        int opk = (s < 4) ? pk0 : pk1;
        float ov = (s < 4) ? v0 : v1;
#pragma unroll
        for (int rg = 0; rg < 4; rg++) {
            int e = (s & 3) * 16 + quad * 4 + rg;
            float ve = __shfl(ov, e, 64);
            int pe = __shfl(opk, e, 64) & 0x1FFFFFF;
            if (FO == 32) {
                uint32 val = pack_bf16x2(acc[s][0][rg] * ve, acc[s][1][rg] * ve);
                y[(size_t)pe * 16 + ln15] = val;               // 64 B/edge over 16 lanes
            } else {
                ((ushort*)y)[(size_t)pe * 16 + ln15] = bf16_1(acc[s][0][rg] * ve);
            }
        }
    }
}

// ------- stage B: segmented sum over dst-sorted y, fused bias(+relu) ------
template <int FO, bool RELU, bool BF16OUT>
__global__ __launch_bounds__(256) void k_segB(const uint32* __restrict__ y,
                                              const int* __restrict__ dst_base,
                                              const float* __restrict__ bias,
                                              void* __restrict__ outp) {
    const int UPR = FO / 2;        // uints per row
    const int QL = UPR / 4;        // u32x4 chunks per row: 4 / 2
    const int RPI = 64 / QL;       // rows per iteration: 16 / 32
    const bool ILV = (FO == 32);   // interleaved (c, c+16) pair layout
    int t = threadIdx.x, lane = t & 63, wv = t >> 6;
    int dst = blockIdx.x * 4 + wv;
    if (dst >= NNODES) return;
    int s = dst_base[dst], e2 = dst_base[dst + 1];
    int q = lane % QL, r = lane / QL;
    float acc[8];
#pragma unroll
    for (int j = 0; j < 8; j++) acc[j] = 0.f;
    for (int i = s + r; i < e2; i += RPI) {
        u32x4 u = __builtin_nontemporal_load((const u32x4*)(y + (size_t)i * UPR + 4 * q));
        acc[0] += unpack_lo(u.x); acc[1] += unpack_hi(u.x);
        acc[2] += unpack_lo(u.y); acc[3] += unpack_hi(u.y);
        acc[4] += unpack_lo(u.z); acc[5] += unpack_hi(u.z);
        acc[6] += unpack_lo(u.w); acc[7] += unpack_hi(u.w);
    }
#pragma unroll
    for (int off = 32; off >= QL; off >>= 1)
#pragma unroll
        for (int j = 0; j < 8; j++) acc[j] += __shfl_down(acc[j], off, 64);
    if (lane < QL) {
        float o[8];
        if (ILV) {
            // acc[2j] = col 4q+j ; acc[2j+1] = col 4q+16+j
#pragma unroll
            for (int j = 0; j < 4; j++) {
                o[2 * j]     = acc[2 * j]     + bias[4 * q + j];
                o[2 * j + 1] = acc[2 * j + 1] + bias[4 * q + 16 + j];
                if (RELU) { o[2 * j] = fmaxf(o[2 * j], 0.f); o[2 * j + 1] = fmaxf(o[2 * j + 1], 0.f); }
            }
        } else {
#pragma unroll
            for (int j = 0; j < 8; j++) {
                o[j] = acc[j] + bias[8 * q + j];
                if (RELU) o[j] = fmaxf(o[j], 0.f);
            }
        }
        if (BF16OUT) {
            if (ILV) {  // write sequential-pair bf16 rows (Xb layout for layer 2)
                u32x2 a0, a1;
                a0.x = pack_bf16x2(o[0], o[2]); a0.y = pack_bf16x2(o[4], o[6]);   // cols 4q..4q+3
                a1.x = pack_bf16x2(o[1], o[3]); a1.y = pack_bf16x2(o[5], o[7]);   // cols 4q+16..19
                ((u32x2*)outp)[(size_t)dst * 8 + q] = a0;
                ((u32x2*)outp)[(size_t)dst * 8 + 4 + q] = a1;
            } else {
                u32x4 pk;
                pk.x = pack_bf16x2(o[0], o[1]); pk.y = pack_bf16x2(o[2], o[3]);
                pk.z = pack_bf16x2(o[4], o[5]); pk.w = pack_bf16x2(o[6], o[7]);
                ((u32x4*)outp)[(size_t)dst * QL + q] = pk;
            }
        } else {
            float4* op = (float4*)outp;
            op[(size_t)dst * (FO / 4) + 2 * q]     = make_float4(o[0], o[1], o[2], o[3]);
            op[(size_t)dst * (FO / 4) + 2 * q + 1] = make_float4(o[4], o[5], o[6], o[7]);
        }
    }
}

extern "C" void kernel_launch(void* const* d_in, const int* in_sizes, int n_in,
                              void* d_out, int out_size, void* d_ws, size_t ws_size,
                              hipStream_t stream) {
    const float* features = (const float*)d_in[0];
    const float* vals     = (const float*)d_in[1];
    const float* comps1   = (const float*)d_in[2];
    const float* bases1   = (const float*)d_in[3];
    const float* bias1    = (const float*)d_in[4];
    const float* comps2   = (const float*)d_in[5];
    const float* bases2   = (const float*)d_in[6];
    const float* bias2    = (const float*)d_in[7];
    const int*   rows     = (const int*)d_in[8];
    const int*   cols     = (const int*)d_in[9];
    float* out = (float*)d_out;

    // ---- workspace layout (4-byte element offsets; all blocks 16 B-aligned) ----
    float* ws = (float*)d_ws;
    size_t o = 0;
    ushort* Wb1 = (ushort*)(ws + o); o += RREL * FIN * EDIM / 2;        // 26112
    ushort* Wb2 = (ushort*)(ws + o); o += RREL * EDIM * CDIM / 2;       // 13056
    o = (o + 3) & ~(size_t)3;
    uint32* Xb  = (uint32*)(ws + o); o += (size_t)NNODES * (FIN / 2);   // 0.8M
    uint32* h1b = (uint32*)(ws + o); o += (size_t)NNODES * (EDIM / 2);  // 0.8M
    int* s_pk  = (int*)(ws + o); o += CAP_;
    int* s_src = (int*)(ws + o); o += CAP_;
    float* s_val = ws + o;       o += CAP_;
    // contiguous zero region: rel_cnt, dst_rank
    int* rel_cnt  = (int*)(ws + o); o += RREL + 1;
    int* dst_rank = (int*)(ws + o); o += NNODES;
    int* rel_cur  = (int*)(ws + o); o += RREL;
    int* pad_base = (int*)(ws + o); o += RREL + 1;
    o = (o + 3) & ~(size_t)3;
    int* dst_base = (int*)(ws + o); o += NNODES + 4;
    o = (o + 3) & ~(size_t)3;
    uint32* y = (uint32*)(ws + o);     // (NNZ_+1) rows x 16 uints, reused both layers

    const int NB = (NNZ_ + EPB - 1) / EPB;   // 489

    hipMemsetAsync(rel_cnt, 0, (RREL + 1 + NNODES) * sizeof(int), stream);

    k_weights<<<(RREL * FIN * EDIM + 255) / 256, 256, 0, stream>>>(comps1, bases1, comps2, bases2, Wb1, Wb2);
    k_tobf16<<<(NNODES * FIN / 2 + 255) / 256, 256, 0, stream>>>((const float2*)features, Xb, NNODES * FIN / 2);
    k_relhist<<<NB, 1024, 0, stream>>>(rows, rel_cnt);
    k_relscan<<<1, 64, 0, stream>>>(rel_cnt, pad_base, rel_cur);
    k_padfill<<<RREL + 1, 64, 0, stream>>>(rel_cnt, pad_base, s_pk, s_src, s_val);
    k_scatter<<<NB, 1024, 0, stream>>>(rows, cols, vals, rel_cur, dst_rank, s_pk, s_src, s_val);
    k_scan<<<1, 1024, 0, stream>>>(dst_rank, dst_base);
    k_translate<<<CAP_ / 4 / 256, 256, 0, stream>>>(s_pk, dst_base);

    k_edgeA<EDIM><<<CAP_ / 512, 256, 0, stream>>>(s_pk, s_src, s_val, (const u32x4*)Xb,
                                                  (const u32x4*)Wb1, y);
    k_segB<EDIM, true, true><<<(NNODES + 3) / 4, 256, 0, stream>>>(y, dst_base, bias1, h1b);
    k_edgeA<CDIM><<<CAP_ / 512, 256, 0, stream>>>(s_pk, s_src, s_val, (const u32x4*)h1b,
                                                  (const u32x4*)Wb2, y);
    k_segB<CDIM, false, false><<<(NNODES + 3) / 4, 256, 0, stream>>>(y, dst_base, bias2, out);
}

// Round 11
// 388.817 us; speedup vs baseline: 2.3952x; 1.0091x over previous
//
#include <hip/hip_runtime.h>

#define NNODES 50000
#define RREL 51
#define FIN 32
#define EDIM 32
#define CDIM 16
#define BB 30
#define NNZ_ 2000000
#define CAP_ 2000896   // ceil((NNZ_ + 51*15)/512)*512 : padded edge capacity
#define EPB 4096       // edges per block in hist/scatter
#define MAXDEG 128     // virtual per-dst rank stride (max true degree ~78)
#define RSTR 32        // dst_rank line-padding stride (ints): 1 counter / 128B line

typedef unsigned int uint32;
typedef unsigned short ushort;
typedef uint32 u32x2 __attribute__((ext_vector_type(2)));
typedef uint32 u32x4 __attribute__((ext_vector_type(4)));
typedef short bf16x8 __attribute__((ext_vector_type(8)));
typedef float f32x4 __attribute__((ext_vector_type(4)));

// ---------- bf16 helpers (manual RNE) ----------
static __device__ __forceinline__ uint32 pack_bf16x2(float a, float b) {
    uint32 ua = __builtin_bit_cast(uint32, a);
    uint32 ub = __builtin_bit_cast(uint32, b);
    ua += 0x7fffu + ((ua >> 16) & 1u);
    ub += 0x7fffu + ((ub >> 16) & 1u);
    return (ua >> 16) | (ub & 0xffff0000u);
}
static __device__ __forceinline__ ushort bf16_1(float x) {
    uint32 u = __builtin_bit_cast(uint32, x);
    u += 0x7fffu + ((u >> 16) & 1u);
    return (ushort)(u >> 16);
}
static __device__ __forceinline__ float unpack_lo(uint32 u) { return __builtin_bit_cast(float, u << 16); }
static __device__ __forceinline__ float unpack_hi(uint32 u) { return __builtin_bit_cast(float, u & 0xffff0000u); }

// ---- weight build into MFMA-B-swizzled bf16 layout: Wb[r][kchunk][n][j], k=8*kchunk+j ----
__global__ void k_weights(const float* __restrict__ comps1, const float* __restrict__ bases1,
                          const float* __restrict__ comps2, const float* __restrict__ bases2,
                          ushort* __restrict__ Wb1, ushort* __restrict__ Wb2) {
    int i = blockIdx.x * 256 + threadIdx.x;
    if (i < RREL * FIN * EDIM) {          // (r, f, e): f = k index, e = n index
        int r = i >> 10, fe = i & 1023, f = fe >> 5, e = fe & 31;
        float acc = 0.f;
#pragma unroll
        for (int b = 0; b < BB; b++) acc += comps1[r * BB + b] * bases1[b * 1024 + fe];
        Wb1[((r * 4 + (f >> 3)) * 32 + e) * 8 + (f & 7)] = bf16_1(acc);
    }
    if (i < RREL * EDIM * CDIM) {         // (r, k, c)
        int r = i >> 9, ec = i & 511, kk = ec >> 4, c = ec & 15;
        float acc = 0.f;
#pragma unroll
        for (int b = 0; b < BB; b++) acc += comps2[r * BB + b] * bases2[b * 512 + ec];
        Wb2[((r * 4 + (kk >> 3)) * 16 + c) * 8 + (kk & 7)] = bf16_1(acc);
    }
}

// ---------------- fp32 features -> packed bf16 rows (64 B/row, L2-resident) ----------
__global__ void k_tobf16(const float2* __restrict__ src, uint32* __restrict__ dst, int n2) {
    int i = blockIdx.x * 256 + threadIdx.x;
    if (i < n2) {
        float2 f = src[i];
        dst[i] = pack_bf16x2(f.x, f.y);
    }
}

// ------------- relation histogram only: LDS atomics, streaming read -------------
__global__ __launch_bounds__(1024) void k_relhist(const int* __restrict__ rows,
                                                  int* __restrict__ rel_cnt) {
    __shared__ int lc[RREL];
    int t = threadIdx.x;
    if (t < RREL) lc[t] = 0;
    __syncthreads();
    size_t k = (size_t)blockIdx.x * EPB + (size_t)t * 4;
    int rr[4];
    if (k + 4 <= NNZ_) {
        int4 rw = *(const int4*)(rows + k);
        rr[0] = rw.x; rr[1] = rw.y; rr[2] = rw.z; rr[3] = rw.w;
    } else {
#pragma unroll
        for (int j = 0; j < 4; j++) rr[j] = (k + j < NNZ_) ? rows[k + j] : -1;
    }
#pragma unroll
    for (int j = 0; j < 4; j++)
        if (rr[j] >= 0) atomicAdd(&lc[rr[j] / NNODES], 1);
    __syncthreads();
    if (t < RREL) atomicAdd(&rel_cnt[t], lc[t]);
}

// ---- tiny 16-aligned rel prefix ----
__global__ void k_relscan(const int* __restrict__ rel_cnt, int* __restrict__ pad_base,
                          int* __restrict__ rel_cur) {
    if (threadIdx.x == 0) {
        int a = 0;
        for (int r = 0; r < RREL; r++) {
            pad_base[r] = a; rel_cur[r] = a;
            a += (rel_cnt[r] + 15) & ~15;
        }
        pad_base[RREL] = a;
    }
}

// fill padding gaps with dummy edges (rel = segment rel so subtiles stay rel-uniform)
__global__ void k_padfill(const int* __restrict__ rel_cnt, const int* __restrict__ pad_base,
                          int* __restrict__ s_pk, int* __restrict__ s_src,
                          float* __restrict__ s_val) {
    int r = blockIdx.x;
    int start, end, relv;
    if (r < RREL) { start = pad_base[r] + rel_cnt[r]; end = pad_base[r + 1]; relv = r; }
    else { start = pad_base[RREL]; end = CAP_; relv = 0; }
    uint32 pdum = (uint32)NNODES * MAXDEG;   // virtual p -> maps to scratch row after translate
    for (int i = start + threadIdx.x; i < end; i += 64) {
        s_pk[i] = (int)(((uint32)relv << 25) | pdum);
        s_src[i] = 0;
        s_val[i] = 0.f;
    }
}

// ------ LDS-token counting sort by relation + VIRTUAL dst-rank (line-padded atomic) ------
__global__ __launch_bounds__(1024) void k_scatter(const int* __restrict__ rows, const int* __restrict__ cols,
                                                  const float* __restrict__ vals, int* __restrict__ rel_cur,
                                                  int* __restrict__ dst_rank,
                                                  int* __restrict__ s_pk, int* __restrict__ s_src,
                                                  float* __restrict__ s_val) {
    __shared__ int lcnt[RREL], lbase[RREL], gbase[RREL];
    __shared__ int stotal;
    __shared__ uint32 st[EPB];          // token: (dst<<12) | local_idx
    int t = threadIdx.x;
    size_t base = (size_t)blockIdx.x * EPB;
    if (t < RREL) lcnt[t] = 0;
    __syncthreads();
    size_t k = base + (size_t)t * 4;
    int relv[4], dstv[4];
    {
        int rr[4];
        if (k + 4 <= NNZ_) {
            int4 rw = *(const int4*)(rows + k);
            rr[0] = rw.x; rr[1] = rw.y; rr[2] = rw.z; rr[3] = rw.w;
        } else {
#pragma unroll
            for (int j = 0; j < 4; j++) rr[j] = (k + j < NNZ_) ? rows[k + j] : -1;
        }
#pragma unroll
        for (int j = 0; j < 4; j++) {
            if (rr[j] >= 0) {
                int rel = rr[j] / NNODES;
                relv[j] = rel;
                dstv[j] = rr[j] - rel * NNODES;
                atomicAdd(&lcnt[rel], 1);
            } else relv[j] = -1;
        }
    }
    __syncthreads();
    if (t < 64) {                       // wave-0 scan of 51 bucket counts + global reserve
        int v = (t < RREL) ? lcnt[t] : 0;
        int sum = v;
#pragma unroll
        for (int off = 1; off < 64; off <<= 1) {
            int u = __shfl_up(sum, off, 64);
            if (t >= off) sum += u;
        }
        if (t < RREL) { lbase[t] = sum - v; gbase[t] = atomicAdd(&rel_cur[t], v); }
        if (t == RREL - 1) stotal = sum;
    }
    __syncthreads();
    if (t < RREL) lcnt[t] = 0;
    __syncthreads();
#pragma unroll
    for (int j = 0; j < 4; j++) {
        int rel = relv[j];
        if (rel >= 0) {
            int slot = lbase[rel] + atomicAdd(&lcnt[rel], 1);
            st[slot] = ((uint32)dstv[j] << 12) | (uint32)(t * 4 + j);
        }
    }
    __syncthreads();
    int total = stotal;
#pragma unroll
    for (int i = 0; i < 4; i++) {
        int s2 = t + i * 1024;
        if (s2 < total) {
            uint32 u = st[s2];
            int dst = (int)(u >> 12);
            // one rank counter per 128B line: kills same-line RMW serialization
            int p = dst * MAXDEG + atomicAdd(&dst_rank[(size_t)dst * RSTR], 1);
            size_t orig = base + (u & 4095u);
            int rel = rows[orig] / NNODES;
            int g = gbase[rel] + (s2 - lbase[rel]);
            s_pk[g] = (int)(((uint32)rel << 25) | (uint32)p);
            s_src[g] = cols[orig];
            s_val[g] = vals[orig];
        }
    }
}

// ---- compact line-padded dst_rank -> dense dst_cnt (grid-parallel) ----
__global__ void k_compact(const int* __restrict__ dst_rank, int* __restrict__ dst_cnt) {
    int i = blockIdx.x * 256 + threadIdx.x;
    if (i < NNODES) dst_cnt[i] = dst_rank[(size_t)i * RSTR];
}

// ---- single-block scan: dense dst_cnt -> dst_base[0..N] (int4) ----
__global__ __launch_bounds__(1024) void k_scan(const int* __restrict__ cnt, int* __restrict__ base) {
    __shared__ int ssum[1024];
    int t = threadIdx.x;
    const int CH = 52;                 // 13 int4s per thread; 1024*52 >= NNODES
    int lo = t * CH;
    int s = 0;
#pragma unroll
    for (int c = 0; c < 13; c++) {
        int i = lo + c * 4;
        if (i + 4 <= NNODES) {
            int4 q = *(const int4*)(cnt + i);
            s += q.x + q.y + q.z + q.w;
        } else {
            for (int j = 0; j < 4; j++) if (i + j < NNODES) s += cnt[i + j];
        }
    }
    ssum[t] = s;
    __syncthreads();
    for (int off = 1; off < 1024; off <<= 1) {
        int u = (t >= off) ? ssum[t - off] : 0;
        __syncthreads();
        ssum[t] += u;
        __syncthreads();
    }
    int run = (t == 0) ? 0 : ssum[t - 1];
#pragma unroll
    for (int c = 0; c < 13; c++) {
        int i = lo + c * 4;
        if (i + 4 <= NNODES) {
            int4 q = *(const int4*)(cnt + i);
            int4 w;
            w.x = run; run += q.x; w.y = run; run += q.y;
            w.z = run; run += q.z; w.w = run; run += q.w;
            *(int4*)(base + i) = w;
        } else {
            for (int j = 0; j < 4; j++) if (i + j < NNODES) { base[i + j] = run; run += cnt[i + j]; }
        }
    }
    if (t == 1023) base[NNODES] = run;   // tail threads have empty chunks -> run == total
}

// ---- translate virtual p -> compact dst-sorted slot: p' = dst_base[p/128] + p%128 ----
__global__ __launch_bounds__(256) void k_translate(int* __restrict__ s_pk,
                                                   const int* __restrict__ dst_base) {
    int i = blockIdx.x * 256 + threadIdx.x;     // CAP_/4 int4s, grid sized exactly
    int4 v = ((const int4*)s_pk)[i];
    int* c = &v.x;
#pragma unroll
    for (int j = 0; j < 4; j++) {
        uint32 pk = (uint32)c[j];
        uint32 p = pk & 0x1FFFFFFu;
        int dst = (int)(p >> 7);                // MAXDEG = 128
        int compact = dst_base[dst] + (int)(p & 127u);
        c[j] = (int)((pk & 0xFE000000u) | (uint32)compact);
    }
    ((int4*)s_pk)[i] = v;
}

// ------- stage A (MFMA): y[p] = bf16( val * (Xb[src] @ W[rel]) ), C-layout stores -------
// FO=32: y row = 16 uints, uint i holds cols (i, i+16)  [interleaved pairs]
// FO=16: y row = 16 ushorts, sequential cols
template <int FO>
__global__ __launch_bounds__(256) void k_edgeA(const int* __restrict__ s_pk,
                                               const int* __restrict__ s_src,
                                               const float* __restrict__ s_val,
                                               const u32x4* __restrict__ Xb,
                                               const u32x4* __restrict__ Wb,
                                               uint32* __restrict__ y) {
    const int NT = FO / 16;          // N-tiles: 2 / 1
    const int NW = (FO == 32) ? 32 : 16;
    int t = threadIdx.x, lane = t & 63, wv = t >> 6;
    int ln15 = lane & 15, quad = lane >> 4;
    size_t k0 = (size_t)blockIdx.x * 512 + wv * 128;

    int pk0 = s_pk[k0 + lane],  pk1 = s_pk[k0 + 64 + lane];
    int sc0 = s_src[k0 + lane], sc1 = s_src[k0 + 64 + lane];
    float v0 = s_val[k0 + lane], v1 = s_val[k0 + 64 + lane];

    f32x4 acc[8][NT];
    const f32x4 zero = {0.f, 0.f, 0.f, 0.f};
#pragma unroll
    for (int s = 0; s < 8; s++) {
        int osc = (s < 4) ? sc0 : sc1;
        int opk = (s < 4) ? pk0 : pk1;
        int srcs = __shfl(osc, (s & 3) * 16 + ln15, 64);
        int rels = (int)(((uint32)__builtin_amdgcn_readfirstlane(__shfl(opk, (s & 3) * 16, 64))) >> 25);
        bf16x8 a = __builtin_bit_cast(bf16x8, Xb[(size_t)srcs * 4 + quad]);
#pragma unroll
        for (int tt = 0; tt < NT; tt++) {
            bf16x8 b = __builtin_bit_cast(bf16x8, Wb[(rels * 4 + quad) * NW + ln15 + 16 * tt]);
            acc[s][tt] = __builtin_amdgcn_mfma_f32_16x16x32_bf16(a, b, zero, 0, 0, 0);
        }
    }

    // epilogue in C-layout: edge e = (s&3)*16 + quad*4 + rg is spread over 16 lanes (ln15)
#pragma unroll
    for (int s = 0; s < 8; s++) {
        int opk = (s < 4) ? pk0 : pk1;
        float ov = (s < 4) ? v0 : v1;
#pragma unroll
        for (int rg = 0; rg < 4; rg++) {
            int e = (s & 3) * 16 + quad * 4 + rg;
            float ve = __shfl(ov, e, 64);
            int pe = __shfl(opk, e, 64) & 0x1FFFFFF;
            if (FO == 32) {
                uint32 val = pack_bf16x2(acc[s][0][rg] * ve, acc[s][1][rg] * ve);
                y[(size_t)pe * 16 + ln15] = val;               // 64 B/edge over 16 lanes
            } else {
                ((ushort*)y)[(size_t)pe * 16 + ln15] = bf16_1(acc[s][0][rg] * ve);
            }
        }
    }
}

// ------- stage B: segmented sum over dst-sorted y, fused bias(+relu) ------
template <int FO, bool RELU, bool BF16OUT>
__global__ __launch_bounds__(256) void k_segB(const uint32* __restrict__ y,
                                              const int* __restrict__ dst_base,
                                              const float* __restrict__ bias,
                                              void* __restrict__ outp) {
    const int UPR = FO / 2;        // uints per row
    const int QL = UPR / 4;        // u32x4 chunks per row: 4 / 2
    const int RPI = 64 / QL;       // rows per iteration: 16 / 32
    const bool ILV = (FO == 32);   // interleaved (c, c+16) pair layout
    int t = threadIdx.x, lane = t & 63, wv = t >> 6;
    int dst = blockIdx.x * 4 + wv;
    if (dst >= NNODES) return;
    int s = dst_base[dst], e2 = dst_base[dst + 1];
    int q = lane % QL, r = lane / QL;
    float acc[8];
#pragma unroll
    for (int j = 0; j < 8; j++) acc[j] = 0.f;
    for (int i = s + r; i < e2; i += RPI) {
        u32x4 u = __builtin_nontemporal_load((const u32x4*)(y + (size_t)i * UPR + 4 * q));
        acc[0] += unpack_lo(u.x); acc[1] += unpack_hi(u.x);
        acc[2] += unpack_lo(u.y); acc[3] += unpack_hi(u.y);
        acc[4] += unpack_lo(u.z); acc[5] += unpack_hi(u.z);
        acc[6] += unpack_lo(u.w); acc[7] += unpack_hi(u.w);
    }
#pragma unroll
    for (int off = 32; off >= QL; off >>= 1)
#pragma unroll
        for (int j = 0; j < 8; j++) acc[j] += __shfl_down(acc[j], off, 64);
    if (lane < QL) {
        float o[8];
        if (ILV) {
            // acc[2j] = col 4q+j ; acc[2j+1] = col 4q+16+j
#pragma unroll
            for (int j = 0; j < 4; j++) {
                o[2 * j]     = acc[2 * j]     + bias[4 * q + j];
                o[2 * j + 1] = acc[2 * j + 1] + bias[4 * q + 16 + j];
                if (RELU) { o[2 * j] = fmaxf(o[2 * j], 0.f); o[2 * j + 1] = fmaxf(o[2 * j + 1], 0.f); }
            }
        } else {
#pragma unroll
            for (int j = 0; j < 8; j++) {
                o[j] = acc[j] + bias[8 * q + j];
                if (RELU) o[j] = fmaxf(o[j], 0.f);
            }
        }
        if (BF16OUT) {
            if (ILV) {  // write sequential-pair bf16 rows (Xb layout for layer 2)
                u32x2 a0, a1;
                a0.x = pack_bf16x2(o[0], o[2]); a0.y = pack_bf16x2(o[4], o[6]);   // cols 4q..4q+3
                a1.x = pack_bf16x2(o[1], o[3]); a1.y = pack_bf16x2(o[5], o[7]);   // cols 4q+16..19
                ((u32x2*)outp)[(size_t)dst * 8 + q] = a0;
                ((u32x2*)outp)[(size_t)dst * 8 + 4 + q] = a1;
            } else {
                u32x4 pk;
                pk.x = pack_bf16x2(o[0], o[1]); pk.y = pack_bf16x2(o[2], o[3]);
                pk.z = pack_bf16x2(o[4], o[5]); pk.w = pack_bf16x2(o[6], o[7]);
                ((u32x4*)outp)[(size_t)dst * QL + q] = pk;
            }
        } else {
            float4* op = (float4*)outp;
            op[(size_t)dst * (FO / 4) + 2 * q]     = make_float4(o[0], o[1], o[2], o[3]);
            op[(size_t)dst * (FO / 4) + 2 * q + 1] = make_float4(o[4], o[5], o[6], o[7]);
        }
    }
}

extern "C" void kernel_launch(void* const* d_in, const int* in_sizes, int n_in,
                              void* d_out, int out_size, void* d_ws, size_t ws_size,
                              hipStream_t stream) {
    const float* features = (const float*)d_in[0];
    const float* vals     = (const float*)d_in[1];
    const float* comps1   = (const float*)d_in[2];
    const float* bases1   = (const float*)d_in[3];
    const float* bias1    = (const float*)d_in[4];
    const float* comps2   = (const float*)d_in[5];
    const float* bases2   = (const float*)d_in[6];
    const float* bias2    = (const float*)d_in[7];
    const int*   rows     = (const int*)d_in[8];
    const int*   cols     = (const int*)d_in[9];
    float* out = (float*)d_out;

    // ---- workspace layout: byte-identical to round 8 (158.97 MB, proven fit) ----
    // dst_rank is a 6.4 MB line-padded counter table ALIASED into the head of y:
    // dead after k_compact, y first written in k_edgeA -> disjoint lifetimes.
    float* ws = (float*)d_ws;
    size_t o = 0;
    ushort* Wb1 = (ushort*)(ws + o); o += RREL * FIN * EDIM / 2;        // 26112
    ushort* Wb2 = (ushort*)(ws + o); o += RREL * EDIM * CDIM / 2;       // 13056
    o = (o + 3) & ~(size_t)3;
    uint32* Xb  = (uint32*)(ws + o); o += (size_t)NNODES * (FIN / 2);   // 0.8M
    uint32* h1b = (uint32*)(ws + o); o += (size_t)NNODES * (EDIM / 2);  // 0.8M
    int* s_pk  = (int*)(ws + o); o += CAP_;
    int* s_src = (int*)(ws + o); o += CAP_;
    float* s_val = ws + o;       o += CAP_;
    int* rel_cnt  = (int*)(ws + o); o += RREL + 1;
    int* dst_cnt  = (int*)(ws + o); o += NNODES;
    int* rel_cur  = (int*)(ws + o); o += RREL;
    int* pad_base = (int*)(ws + o); o += RREL + 1;
    o = (o + 3) & ~(size_t)3;
    int* dst_base = (int*)(ws + o); o += NNODES + 4;
    o = (o + 3) & ~(size_t)3;
    uint32* y = (uint32*)(ws + o);     // (NNZ_+1) rows x 16 uints, reused both layers
    int* dst_rank = (int*)y;           // ALIAS: first NNODES*RSTR ints of y

    const int NB = (NNZ_ + EPB - 1) / EPB;   // 489

    hipMemsetAsync(rel_cnt, 0, (RREL + 1) * sizeof(int), stream);
    hipMemsetAsync(dst_rank, 0, (size_t)NNODES * RSTR * sizeof(int), stream);

    k_weights<<<(RREL * FIN * EDIM + 255) / 256, 256, 0, stream>>>(comps1, bases1, comps2, bases2, Wb1, Wb2);
    k_tobf16<<<(NNODES * FIN / 2 + 255) / 256, 256, 0, stream>>>((const float2*)features, Xb, NNODES * FIN / 2);
    k_relhist<<<NB, 1024, 0, stream>>>(rows, rel_cnt);
    k_relscan<<<1, 64, 0, stream>>>(rel_cnt, pad_base, rel_cur);
    k_padfill<<<RREL + 1, 64, 0, stream>>>(rel_cnt, pad_base, s_pk, s_src, s_val);
    k_scatter<<<NB, 1024, 0, stream>>>(rows, cols, vals, rel_cur, dst_rank, s_pk, s_src, s_val);
    k_compact<<<(NNODES + 255) / 256, 256, 0, stream>>>(dst_rank, dst_cnt);
    k_scan<<<1, 1024, 0, stream>>>(dst_cnt, dst_base);
    k_translate<<<CAP_ / 4 / 256, 256, 0, stream>>>(s_pk, dst_base);

    k_edgeA<EDIM><<<CAP_ / 512, 256, 0, stream>>>(s_pk, s_src, s_val, (const u32x4*)Xb,
                                                  (const u32x4*)Wb1, y);
    k_segB<EDIM, true, true><<<(NNODES + 3) / 4, 256, 0, stream>>>(y, dst_base, bias1, h1b);
    k_edgeA<CDIM><<<CAP_ / 512, 256, 0, stream>>>(s_pk, s_src, s_val, (const u32x4*)h1b,
                                                  (const u32x4*)Wb2, y);
    k_segB<CDIM, false, false><<<(NNODES + 3) / 4, 256, 0, stream>>>(y, dst_base, bias2, out);
}

// Round 12
// 381.774 us; speedup vs baseline: 2.4394x; 1.0184x over previous
//
#include <hip/hip_runtime.h>

#define NNODES 50000
#define RREL 51
#define FIN 32
#define EDIM 32
#define CDIM 16
#define BB 30
#define NNZ_ 2000000
#define CAP_ 2000896   // ceil((NNZ_ + 51*15)/512)*512 : padded edge capacity
#define EPB 4096       // edges per block in hist/scatter/bucket
#define NBUK 391       // coarse dst buckets: dst>>7, dst in [0, 50000]

typedef unsigned int uint32;
typedef unsigned short ushort;
typedef uint32 u32x2 __attribute__((ext_vector_type(2)));
typedef uint32 u32x4 __attribute__((ext_vector_type(4)));
typedef short bf16x8 __attribute__((ext_vector_type(8)));
typedef float f32x4 __attribute__((ext_vector_type(4)));

// ---------- bf16 helpers (manual RNE) ----------
static __device__ __forceinline__ uint32 pack_bf16x2(float a, float b) {
    uint32 ua = __builtin_bit_cast(uint32, a);
    uint32 ub = __builtin_bit_cast(uint32, b);
    ua += 0x7fffu + ((ua >> 16) & 1u);
    ub += 0x7fffu + ((ub >> 16) & 1u);
    return (ua >> 16) | (ub & 0xffff0000u);
}
static __device__ __forceinline__ ushort bf16_1(float x) {
    uint32 u = __builtin_bit_cast(uint32, x);
    u += 0x7fffu + ((u >> 16) & 1u);
    return (ushort)(u >> 16);
}
static __device__ __forceinline__ float unpack_lo(uint32 u) { return __builtin_bit_cast(float, u << 16); }
static __device__ __forceinline__ float unpack_hi(uint32 u) { return __builtin_bit_cast(float, u & 0xffff0000u); }

// ---- weight build into MFMA-B-swizzled bf16 layout: Wb[r][kchunk][n][j], k=8*kchunk+j ----
__global__ void k_weights(const float* __restrict__ comps1, const float* __restrict__ bases1,
                          const float* __restrict__ comps2, const float* __restrict__ bases2,
                          ushort* __restrict__ Wb1, ushort* __restrict__ Wb2) {
    int i = blockIdx.x * 256 + threadIdx.x;
    if (i < RREL * FIN * EDIM) {          // (r, f, e): f = k index, e = n index
        int r = i >> 10, fe = i & 1023, f = fe >> 5, e = fe & 31;
        float acc = 0.f;
#pragma unroll
        for (int b = 0; b < BB; b++) acc += comps1[r * BB + b] * bases1[b * 1024 + fe];
        Wb1[((r * 4 + (f >> 3)) * 32 + e) * 8 + (f & 7)] = bf16_1(acc);
    }
    if (i < RREL * EDIM * CDIM) {         // (r, k, c)
        int r = i >> 9, ec = i & 511, kk = ec >> 4, c = ec & 15;
        float acc = 0.f;
#pragma unroll
        for (int b = 0; b < BB; b++) acc += comps2[r * BB + b] * bases2[b * 512 + ec];
        Wb2[((r * 4 + (kk >> 3)) * 16 + c) * 8 + (kk & 7)] = bf16_1(acc);
    }
}

// ---------------- fp32 features -> packed bf16 rows (64 B/row, L2-resident) ----------
__global__ void k_tobf16(const float2* __restrict__ src, uint32* __restrict__ dst, int n2) {
    int i = blockIdx.x * 256 + threadIdx.x;
    if (i < n2) {
        float2 f = src[i];
        dst[i] = pack_bf16x2(f.x, f.y);
    }
}

// ------------- relation histogram only: LDS atomics, streaming read -------------
__global__ __launch_bounds__(1024) void k_relhist(const int* __restrict__ rows,
                                                  int* __restrict__ rel_cnt) {
    __shared__ int lc[RREL];
    int t = threadIdx.x;
    if (t < RREL) lc[t] = 0;
    __syncthreads();
    size_t k = (size_t)blockIdx.x * EPB + (size_t)t * 4;
    int rr[4];
    if (k + 4 <= NNZ_) {
        int4 rw = *(const int4*)(rows + k);
        rr[0] = rw.x; rr[1] = rw.y; rr[2] = rw.z; rr[3] = rw.w;
    } else {
#pragma unroll
        for (int j = 0; j < 4; j++) rr[j] = (k + j < NNZ_) ? rows[k + j] : -1;
    }
#pragma unroll
    for (int j = 0; j < 4; j++)
        if (rr[j] >= 0) atomicAdd(&lc[rr[j] / NNODES], 1);
    __syncthreads();
    if (t < RREL) atomicAdd(&rel_cnt[t], lc[t]);
}

// ---- tiny 16-aligned rel prefix ----
__global__ void k_relscan(const int* __restrict__ rel_cnt, int* __restrict__ pad_base,
                          int* __restrict__ rel_cur) {
    if (threadIdx.x == 0) {
        int a = 0;
        for (int r = 0; r < RREL; r++) {
            pad_base[r] = a; rel_cur[r] = a;
            a += (rel_cnt[r] + 15) & ~15;
        }
        pad_base[RREL] = a;
    }
}

// fill padding gaps with dummy edges (rel = segment rel; dst = NNODES -> sorts to tail)
__global__ void k_padfill(const int* __restrict__ rel_cnt, const int* __restrict__ pad_base,
                          int* __restrict__ s_pk, int* __restrict__ s_src,
                          float* __restrict__ s_val, int* __restrict__ buk_cnt) {
    int r = blockIdx.x;
    int start, end, relv;
    if (r < RREL) { start = pad_base[r] + rel_cnt[r]; end = pad_base[r + 1]; relv = r; }
    else { start = pad_base[RREL]; end = CAP_; relv = 0; }
    if (threadIdx.x == 0 && end > start) atomicAdd(&buk_cnt[NBUK - 1], end - start);
    int pkpad = (int)(((uint32)relv << 25) | (uint32)NNODES);
    for (int i = start + threadIdx.x; i < end; i += 64) {
        s_pk[i] = pkpad;
        s_src[i] = 0;
        s_val[i] = 0.f;
    }
}

// ------ LDS-token counting sort by relation; s_pk=(rel<<25)|dst; NO global rank atomics.
// ------ Also merges a 391-bucket coarse dst histogram (non-returning adds).
__global__ __launch_bounds__(1024) void k_scatter(const int* __restrict__ rows, const int* __restrict__ cols,
                                                  const float* __restrict__ vals, int* __restrict__ rel_cur,
                                                  int* __restrict__ buk_cnt,
                                                  int* __restrict__ s_pk, int* __restrict__ s_src,
                                                  float* __restrict__ s_val) {
    __shared__ int lcnt[RREL], lbase[RREL], gbase[RREL];
    __shared__ int bukc[NBUK];
    __shared__ int stotal;
    __shared__ uint32 st[EPB];          // token: (dst<<12) | local_idx
    int t = threadIdx.x;
    size_t base = (size_t)blockIdx.x * EPB;
    if (t < RREL) lcnt[t] = 0;
    if (t < NBUK) bukc[t] = 0;
    __syncthreads();
    size_t k = base + (size_t)t * 4;
    int relv[4], dstv[4];
    {
        int rr[4];
        if (k + 4 <= NNZ_) {
            int4 rw = *(const int4*)(rows + k);
            rr[0] = rw.x; rr[1] = rw.y; rr[2] = rw.z; rr[3] = rw.w;
        } else {
#pragma unroll
            for (int j = 0; j < 4; j++) rr[j] = (k + j < NNZ_) ? rows[k + j] : -1;
        }
#pragma unroll
        for (int j = 0; j < 4; j++) {
            if (rr[j] >= 0) {
                int rel = rr[j] / NNODES;
                relv[j] = rel;
                dstv[j] = rr[j] - rel * NNODES;
                atomicAdd(&lcnt[rel], 1);
                atomicAdd(&bukc[dstv[j] >> 7], 1);
            } else relv[j] = -1;
        }
    }
    __syncthreads();
    if (t < 64) {                       // wave-0 scan of 51 bucket counts + global reserve
        int v = (t < RREL) ? lcnt[t] : 0;
        int sum = v;
#pragma unroll
        for (int off = 1; off < 64; off <<= 1) {
            int u = __shfl_up(sum, off, 64);
            if (t >= off) sum += u;
        }
        if (t < RREL) { lbase[t] = sum - v; gbase[t] = atomicAdd(&rel_cur[t], v); }
        if (t == RREL - 1) stotal = sum;
    }
    if (t < NBUK) atomicAdd(&buk_cnt[t], bukc[t]);   // non-returning merge
    __syncthreads();
    if (t < RREL) lcnt[t] = 0;
    __syncthreads();
#pragma unroll
    for (int j = 0; j < 4; j++) {
        int rel = relv[j];
        if (rel >= 0) {
            int slot = lbase[rel] + atomicAdd(&lcnt[rel], 1);
            st[slot] = ((uint32)dstv[j] << 12) | (uint32)(t * 4 + j);
        }
    }
    __syncthreads();
    int total = stotal;
#pragma unroll
    for (int i = 0; i < 4; i++) {
        int s2 = t + i * 1024;
        if (s2 < total) {
            uint32 u = st[s2];
            int dst = (int)(u >> 12);
            size_t orig = base + (u & 4095u);
            int rel = rows[orig] / NNODES;
            int g = gbase[rel] + (s2 - lbase[rel]);
            s_pk[g] = (int)(((uint32)rel << 25) | (uint32)dst);
            s_src[g] = cols[orig];
            s_val[g] = vals[orig];
        }
    }
}

// ---- tiny exclusive scan over 391 coarse-bucket counts ----
__global__ void k_bukscan(const int* __restrict__ buk_cnt, int* __restrict__ buk_base,
                          int* __restrict__ buk_cur) {
    if (threadIdx.x == 0) {
        int a = 0;
        for (int b = 0; b < NBUK; b++) { buk_base[b] = a; buk_cur[b] = a; a += buk_cnt[b]; }
        buk_base[NBUK] = a;   // == CAP_
    }
}

// ---- coarse bucket partition: tok8[bucket-grouped] = { pk, g } over all CAP_ entries ----
__global__ __launch_bounds__(1024) void k_bucket(const int* __restrict__ s_pk,
                                                 int* __restrict__ buk_cur,
                                                 u32x2* __restrict__ tok8) {
    __shared__ int bukc[NBUK], lbase2[NBUK], gbase2[NBUK];
    __shared__ int ssum[1024];
    __shared__ u32x2 st8[EPB];
    int t = threadIdx.x;
    size_t base = (size_t)blockIdx.x * EPB;
    int total = (int)(((size_t)CAP_ - base < (size_t)EPB) ? ((size_t)CAP_ - base) : (size_t)EPB);
    if (t < NBUK) bukc[t] = 0;
    __syncthreads();
    size_t k = base + (size_t)t * 4;
    int pkv[4], bv[4];
    if (k + 4 <= CAP_) {
        int4 q = *(const int4*)(s_pk + k);
        pkv[0] = q.x; pkv[1] = q.y; pkv[2] = q.z; pkv[3] = q.w;
#pragma unroll
        for (int j = 0; j < 4; j++) bv[j] = (int)(((uint32)pkv[j] & 0x1FFFFFFu) >> 7);
    } else {
#pragma unroll
        for (int j = 0; j < 4; j++) {
            if (k + j < CAP_) { pkv[j] = s_pk[k + j]; bv[j] = (int)(((uint32)pkv[j] & 0x1FFFFFFu) >> 7); }
            else bv[j] = -1;
        }
    }
#pragma unroll
    for (int j = 0; j < 4; j++)
        if (bv[j] >= 0) atomicAdd(&bukc[bv[j]], 1);
    __syncthreads();
    // block-wide exclusive scan over NBUK counts
    int v = (t < NBUK) ? bukc[t] : 0;
    ssum[t] = v;
    __syncthreads();
    for (int off = 1; off < 1024; off <<= 1) {
        int u = (t >= off) ? ssum[t - off] : 0;
        __syncthreads();
        ssum[t] += u;
        __syncthreads();
    }
    if (t < NBUK) { lbase2[t] = ssum[t] - v; gbase2[t] = atomicAdd(&buk_cur[t], v); }
    __syncthreads();
    if (t < NBUK) bukc[t] = 0;
    __syncthreads();
#pragma unroll
    for (int j = 0; j < 4; j++) {
        if (bv[j] >= 0) {
            int slot = lbase2[bv[j]] + atomicAdd(&bukc[bv[j]], 1);
            u32x2 w; w.x = (uint32)pkv[j]; w.y = (uint32)(k + j);
            st8[slot] = w;
        }
    }
    __syncthreads();
    for (int s2 = t; s2 < total; s2 += 1024) {
        u32x2 w = st8[s2];
        int b = (int)((w.x & 0x1FFFFFFu) >> 7);
        tok8[gbase2[b] + (s2 - lbase2[b])] = w;
    }
}

// ---- per-bucket LDS counting sort: assign compact q, write dst_base, rewrite s_pk ----
__global__ __launch_bounds__(256) void k_rank(const u32x2* __restrict__ tok8,
                                              const int* __restrict__ buk_base,
                                              int* __restrict__ dst_base,
                                              int* __restrict__ s_pk) {
    __shared__ int lcnt[128], lexc[128], lrank[128], ssc[128];
    int b = blockIdx.x, t = threadIdx.x;
    int lo = buk_base[b], hi = buk_base[b + 1];
    int d0 = b << 7;
    if (t < 128) lcnt[t] = 0;
    __syncthreads();
    for (int i = lo + t; i < hi; i += 256) {
        int dl = (int)(tok8[i].x & 0x1FFFFFFu) - d0;
        atomicAdd(&lcnt[dl], 1);
    }
    __syncthreads();
    int v = (t < 128) ? lcnt[t] : 0;
    if (t < 128) ssc[t] = v;
    __syncthreads();
    for (int off = 1; off < 128; off <<= 1) {
        int u = (t >= off && t < 128) ? ssc[t - off] : 0;
        __syncthreads();
        if (t < 128) ssc[t] += u;
        __syncthreads();
    }
    if (t < 128) {
        lexc[t] = ssc[t] - v;
        int d = d0 + t;
        if (d <= NNODES) dst_base[d] = lo + lexc[t];
        lrank[t] = 0;
    }
    __syncthreads();
    for (int i = lo + t; i < hi; i += 256) {
        u32x2 w = tok8[i];
        int dl = (int)(w.x & 0x1FFFFFFu) - d0;
        int q = lo + lexc[dl] + atomicAdd(&lrank[dl], 1);
        s_pk[(int)w.y] = (int)((w.x & 0xFE000000u) | (uint32)q);
    }
}

// ------- stage A (MFMA): y[p] = bf16( val * (Xb[src] @ W[rel]) ), C-layout stores -------
// FO=32: y row = 16 uints, uint i holds cols (i, i+16)  [interleaved pairs]
// FO=16: y row = 16 ushorts, sequential cols
template <int FO>
__global__ __launch_bounds__(256) void k_edgeA(const int* __restrict__ s_pk,
                                               const int* __restrict__ s_src,
                                               const float* __restrict__ s_val,
                                               const u32x4* __restrict__ Xb,
                                               const u32x4* __restrict__ Wb,
                                               uint32* __restrict__ y) {
    const int NT = FO / 16;          // N-tiles: 2 / 1
    const int NW = (FO == 32) ? 32 : 16;
    int t = threadIdx.x, lane = t & 63, wv = t >> 6;
    int ln15 = lane & 15, quad = lane >> 4;
    size_t k0 = (size_t)blockIdx.x * 512 + wv * 128;

    int pk0 = s_pk[k0 + lane],  pk1 = s_pk[k0 + 64 + lane];
    int sc0 = s_src[k0 + lane], sc1 = s_src[k0 + 64 + lane];
    float v0 = s_val[k0 + lane], v1 = s_val[k0 + 64 + lane];

    f32x4 acc[8][NT];
    const f32x4 zero = {0.f, 0.f, 0.f, 0.f};
#pragma unroll
    for (int s = 0; s < 8; s++) {
        int osc = (s < 4) ? sc0 : sc1;
        int opk = (s < 4) ? pk0 : pk1;
        int srcs = __shfl(osc, (s & 3) * 16 + ln15, 64);
        int rels = (int)(((uint32)__builtin_amdgcn_readfirstlane(__shfl(opk, (s & 3) * 16, 64))) >> 25);
        bf16x8 a = __builtin_bit_cast(bf16x8, Xb[(size_t)srcs * 4 + quad]);
#pragma unroll
        for (int tt = 0; tt < NT; tt++) {
            bf16x8 b = __builtin_bit_cast(bf16x8, Wb[(rels * 4 + quad) * NW + ln15 + 16 * tt]);
            acc[s][tt] = __builtin_amdgcn_mfma_f32_16x16x32_bf16(a, b, zero, 0, 0, 0);
        }
    }

    // epilogue in C-layout: edge e = (s&3)*16 + quad*4 + rg is spread over 16 lanes (ln15)
#pragma unroll
    for (int s = 0; s < 8; s++) {
        int opk = (s < 4) ? pk0 : pk1;
        float ov = (s < 4) ? v0 : v1;
#pragma unroll
        for (int rg = 0; rg < 4; rg++) {
            int e = (s & 3) * 16 + quad * 4 + rg;
            float ve = __shfl(ov, e, 64);
            int pe = __shfl(opk, e, 64) & 0x1FFFFFF;
            if (FO == 32) {
                uint32 val = pack_bf16x2(acc[s][0][rg] * ve, acc[s][1][rg] * ve);
                y[(size_t)pe * 16 + ln15] = val;               // 64 B/edge over 16 lanes
            } else {
                ((ushort*)y)[(size_t)pe * 16 + ln15] = bf16_1(acc[s][0][rg] * ve);
            }
        }
    }
}

// ------- stage B: segmented sum over dst-sorted y, fused bias(+relu) ------
template <int FO, bool RELU, bool BF16OUT>
__global__ __launch_bounds__(256) void k_segB(const uint32* __restrict__ y,
                                              const int* __restrict__ dst_base,
                                              const float* __restrict__ bias,
                                              void* __restrict__ outp) {
    const int UPR = FO / 2;        // uints per row
    const int QL = UPR / 4;        // u32x4 chunks per row: 4 / 2
    const int RPI = 64 / QL;       // rows per iteration: 16 / 32
    const bool ILV = (FO == 32);   // interleaved (c, c+16) pair layout
    int t = threadIdx.x, lane = t & 63, wv = t >> 6;
    int dst = blockIdx.x * 4 + wv;
    if (dst >= NNODES) return;
    int s = dst_base[dst], e2 = dst_base[dst + 1];
    int q = lane % QL, r = lane / QL;
    float acc[8];
#pragma unroll
    for (int j = 0; j < 8; j++) acc[j] = 0.f;
    for (int i = s + r; i < e2; i += RPI) {
        u32x4 u = __builtin_nontemporal_load((const u32x4*)(y + (size_t)i * UPR + 4 * q));
        acc[0] += unpack_lo(u.x); acc[1] += unpack_hi(u.x);
        acc[2] += unpack_lo(u.y); acc[3] += unpack_hi(u.y);
        acc[4] += unpack_lo(u.z); acc[5] += unpack_hi(u.z);
        acc[6] += unpack_lo(u.w); acc[7] += unpack_hi(u.w);
    }
#pragma unroll
    for (int off = 32; off >= QL; off >>= 1)
#pragma unroll
        for (int j = 0; j < 8; j++) acc[j] += __shfl_down(acc[j], off, 64);
    if (lane < QL) {
        float o[8];
        if (ILV) {
            // acc[2j] = col 4q+j ; acc[2j+1] = col 4q+16+j
#pragma unroll
            for (int j = 0; j < 4; j++) {
                o[2 * j]     = acc[2 * j]     + bias[4 * q + j];
                o[2 * j + 1] = acc[2 * j + 1] + bias[4 * q + 16 + j];
                if (RELU) { o[2 * j] = fmaxf(o[2 * j], 0.f); o[2 * j + 1] = fmaxf(o[2 * j + 1], 0.f); }
            }
        } else {
#pragma unroll
            for (int j = 0; j < 8; j++) {
                o[j] = acc[j] + bias[8 * q + j];
                if (RELU) o[j] = fmaxf(o[j], 0.f);
            }
        }
        if (BF16OUT) {
            if (ILV) {  // write sequential-pair bf16 rows (Xb layout for layer 2)
                u32x2 a0, a1;
                a0.x = pack_bf16x2(o[0], o[2]); a0.y = pack_bf16x2(o[4], o[6]);   // cols 4q..4q+3
                a1.x = pack_bf16x2(o[1], o[3]); a1.y = pack_bf16x2(o[5], o[7]);   // cols 4q+16..19
                ((u32x2*)outp)[(size_t)dst * 8 + q] = a0;
                ((u32x2*)outp)[(size_t)dst * 8 + 4 + q] = a1;
            } else {
                u32x4 pk;
                pk.x = pack_bf16x2(o[0], o[1]); pk.y = pack_bf16x2(o[2], o[3]);
                pk.z = pack_bf16x2(o[4], o[5]); pk.w = pack_bf16x2(o[6], o[7]);
                ((u32x4*)outp)[(size_t)dst * QL + q] = pk;
            }
        } else {
            float4* op = (float4*)outp;
            op[(size_t)dst * (FO / 4) + 2 * q]     = make_float4(o[0], o[1], o[2], o[3]);
            op[(size_t)dst * (FO / 4) + 2 * q + 1] = make_float4(o[4], o[5], o[6], o[7]);
        }
    }
}

extern "C" void kernel_launch(void* const* d_in, const int* in_sizes, int n_in,
                              void* d_out, int out_size, void* d_ws, size_t ws_size,
                              hipStream_t stream) {
    const float* features = (const float*)d_in[0];
    const float* vals     = (const float*)d_in[1];
    const float* comps1   = (const float*)d_in[2];
    const float* bases1   = (const float*)d_in[3];
    const float* bias1    = (const float*)d_in[4];
    const float* comps2   = (const float*)d_in[5];
    const float* bases2   = (const float*)d_in[6];
    const float* bias2    = (const float*)d_in[7];
    const int*   rows     = (const int*)d_in[8];
    const int*   cols     = (const int*)d_in[9];
    float* out = (float*)d_out;

    // ---- workspace layout (4-byte units); ~158.9 MB, slightly under round-11's fit.
    // tok8 (16 MB) ALIASES the head of y: dead after k_rank, y first written in k_edgeA.
    float* ws = (float*)d_ws;
    size_t o = 0;
    ushort* Wb1 = (ushort*)(ws + o); o += RREL * FIN * EDIM / 2;        // 26112
    ushort* Wb2 = (ushort*)(ws + o); o += RREL * EDIM * CDIM / 2;       // 13056
    o = (o + 3) & ~(size_t)3;
    uint32* Xb  = (uint32*)(ws + o); o += (size_t)NNODES * (FIN / 2);   // 0.8M
    uint32* h1b = (uint32*)(ws + o); o += (size_t)NNODES * (EDIM / 2);  // 0.8M
    int* s_pk  = (int*)(ws + o); o += CAP_;
    int* s_src = (int*)(ws + o); o += CAP_;
    float* s_val = ws + o;       o += CAP_;
    // contiguous zero region: rel_cnt .. buk_cnt
    int* rel_cnt  = (int*)(ws + o); o += RREL + 1;       // 52
    int* buk_cnt  = (int*)(ws + o); o += NBUK + 1;       // 392
    int* rel_cur  = (int*)(ws + o); o += RREL;
    int* pad_base = (int*)(ws + o); o += RREL + 1;
    int* buk_base = (int*)(ws + o); o += NBUK + 1;
    int* buk_cur  = (int*)(ws + o); o += NBUK;
    o = (o + 3) & ~(size_t)3;
    int* dst_base = (int*)(ws + o); o += NNODES + 4;
    o = (o + 3) & ~(size_t)3;
    uint32* y = (uint32*)(ws + o);     // CAP_ rows x 16 uints, reused both layers
    u32x2* tok8 = (u32x2*)y;           // ALIAS: first CAP_*8 bytes of y

    const int NB = (NNZ_ + EPB - 1) / EPB;    // 489 (real edges)
    const int NB2 = (CAP_ + EPB - 1) / EPB;   // 489 (padded capacity)

    hipMemsetAsync(rel_cnt, 0, (RREL + 1 + NBUK + 1) * sizeof(int), stream);

    k_weights<<<(RREL * FIN * EDIM + 255) / 256, 256, 0, stream>>>(comps1, bases1, comps2, bases2, Wb1, Wb2);
    k_tobf16<<<(NNODES * FIN / 2 + 255) / 256, 256, 0, stream>>>((const float2*)features, Xb, NNODES * FIN / 2);
    k_relhist<<<NB, 1024, 0, stream>>>(rows, rel_cnt);
    k_relscan<<<1, 64, 0, stream>>>(rel_cnt, pad_base, rel_cur);
    k_padfill<<<RREL + 1, 64, 0, stream>>>(rel_cnt, pad_base, s_pk, s_src, s_val, buk_cnt);
    k_scatter<<<NB, 1024, 0, stream>>>(rows, cols, vals, rel_cur, buk_cnt, s_pk, s_src, s_val);
    k_bukscan<<<1, 64, 0, stream>>>(buk_cnt, buk_base, buk_cur);
    k_bucket<<<NB2, 1024, 0, stream>>>(s_pk, buk_cur, tok8);
    k_rank<<<NBUK, 256, 0, stream>>>(tok8, buk_base, dst_base, s_pk);

    k_edgeA<EDIM><<<CAP_ / 512, 256, 0, stream>>>(s_pk, s_src, s_val, (const u32x4*)Xb,
                                                  (const u32x4*)Wb1, y);
    k_segB<EDIM, true, true><<<(NNODES + 3) / 4, 256, 0, stream>>>(y, dst_base, bias1, h1b);
    k_edgeA<CDIM><<<CAP_ / 512, 256, 0, stream>>>(s_pk, s_src, s_val, (const u32x4*)h1b,
                                                  (const u32x4*)Wb2, y);
    k_segB<CDIM, false, false><<<(NNODES + 3) / 4, 256, 0, stream>>>(y, dst_base, bias2, out);
}